// Round 4
// baseline (348.293 us; speedup 1.0000x reference)
//
#include <hip/hip_runtime.h>

typedef unsigned short u16;
typedef __attribute__((ext_vector_type(4))) unsigned short u16x4;
typedef __attribute__((ext_vector_type(8))) unsigned short u16x8;
typedef __attribute__((ext_vector_type(8))) short short8;
typedef __attribute__((ext_vector_type(4))) float f32x4;

#define DEVI __device__ __forceinline__

DEVI u16 f2b(float f) {
  union { float f; unsigned u; } x; x.f = f;
  unsigned r = (x.u + 0x7fffu + ((x.u >> 16) & 1u)) >> 16;
  return (u16)r;
}
DEVI float b2f(u16 h) {
  union { unsigned u; float f; } x; x.u = ((unsigned)h) << 16;
  return x.f;
}
DEVI f32x4 mfma_bf16(short8 a, short8 b, f32x4 c) {
  return __builtin_amdgcn_mfma_f32_16x16x32_bf16(a, b, c, 0, 0, 0);
}
DEVI void gl2lds16(const u16* g, u16* l) {
  __builtin_amdgcn_global_load_lds((__attribute__((address_space(1))) void*)g,
                                   (__attribute__((address_space(3))) void*)l,
                                   16, 0, 0);
}
// barrier that drains only LDS (lgkmcnt), NOT vmcnt -> global prefetch stays in flight
DEVI void barrier_lds() {
  asm volatile("s_waitcnt lgkmcnt(0)\n\ts_barrier" ::: "memory");
}

// ---------------- fp32 -> bf16 convert (hidden_states) + WbT build ----------------
__global__ void k_cvt(const float* __restrict__ src, u16* __restrict__ dst, int n4,
                      const float* __restrict__ Wb, u16* __restrict__ WbT) {
  int b = blockIdx.x;
  if (b < 4096) {
    int i = b * 256 + threadIdx.x;
    if (i < n4) {
      float4 v = ((const float4*)src)[i];
      u16x4 r; r.x = f2b(v.x); r.y = f2b(v.y); r.z = f2b(v.z); r.w = f2b(v.w);
      ((u16x4*)dst)[i] = r;
    }
  } else {
    int j = (b - 4096) * 256 + threadIdx.x;   // 0..32767
    int n = j >> 11, k = j & 2047;
    WbT[j] = f2b(Wb[k * 16 + n]);
  }
}

// ---------------- 4x tiled transpose fp32[2048][2048] -> bf16 transposed ----------------
__global__ __launch_bounds__(256)
void k_transpose4(const float* __restrict__ s0, const float* __restrict__ s1,
                  const float* __restrict__ s2, const float* __restrict__ s3,
                  u16* __restrict__ d0, u16* __restrict__ d1,
                  u16* __restrict__ d2, u16* __restrict__ d3) {
  const int RC = 2048;
  const float* src = (blockIdx.z == 0) ? s0 : (blockIdx.z == 1) ? s1 : (blockIdx.z == 2) ? s2 : s3;
  u16* dst = (blockIdx.z == 0) ? d0 : (blockIdx.z == 1) ? d1 : (blockIdx.z == 2) ? d2 : d3;
  __shared__ u16 tile[64 * 66];
  int bx = blockIdx.x << 6, by = blockIdx.y << 6;
  int x = threadIdx.x & 63, g = threadIdx.x >> 6;
#pragma unroll
  for (int i = 0; i < 16; ++i) {
    int r = (i << 2) + g;
    tile[x * 66 + r] = f2b(src[(size_t)(by + r) * RC + bx + x]);  // transposed into LDS
  }
  __syncthreads();
#pragma unroll
  for (int i = 0; i < 16; ++i) {
    int r = (i << 2) + g;
    dst[(size_t)(bx + r) * RC + by + x] = tile[r * 66 + x];       // 128B coalesced rows
  }
}

// ============ 8-phase 256x256 bf16 MFMA GEMM, ds_reads pipelined one phase ahead ============
// (round-2 schedule — empirically best: 1 barrier/phase, reads issued one phase before use,
//  compiler emits counted lgkmcnt so MFMAs start as soon as their operands land.)
// C[M][N] = A[M][K] @ BT[N][K]^T. BM=BN=256, BK=64, 512 thr = 8 waves (2x4).
// LDS 128 KiB = {A0,A1,B0,B1} x {slot0,slot1} x (128 rows x 64 k) bf16.
// vmcnt(4) at phi2-end proves all four halves of tile u+1 landed before phi3 issues
// next-tile reads. Stage order: phi0->A1(u+1), phi1->A0(u+2), phi2->B0(u+2), phi3->B1(u+2).
// LDS XOR-swizzled reads; inverse swizzle on the per-lane GLOBAL source (rule 21).
// Split-K via kz: chunk covers K-range [kz*NT*64, ...). FOUT=0: bf16 out; FOUT=1: fp32
// partial to Cf + kz*czstride.

struct StageCtx { size_t go[2]; int lo[2]; };

DEVI void stage_half(const u16* g, const StageCtx& sc, u16* l) {
  gl2lds16(g + sc.go[0], l + sc.lo[0]);
  gl2lds16(g + sc.go[1], l + sc.lo[1]);
}

DEVI void rdA(const u16* h, const int (&aoff)[4][2], short8 (&a)[4][2]) {
#pragma unroll
  for (int m = 0; m < 4; ++m) {
    a[m][0] = *(const short8*)(h + aoff[m][0]);
    a[m][1] = *(const short8*)(h + aoff[m][1]);
  }
}
DEVI void rdB(const u16* h, const int (&boff)[2][2], short8 (&b)[2][2]) {
#pragma unroll
  for (int n = 0; n < 2; ++n) {
    b[n][0] = *(const short8*)(h + boff[n][0]);
    b[n][1] = *(const short8*)(h + boff[n][1]);
  }
}

template <int QA, int QB>
DEVI void mmquad(const short8 (&a)[4][2], const short8 (&b)[2][2], f32x4 (&acc)[8][4]) {
  __builtin_amdgcn_s_setprio(1);
#pragma unroll
  for (int m = 0; m < 4; ++m)
#pragma unroll
    for (int n = 0; n < 2; ++n) {
      acc[(QA << 2) + m][(QB << 1) + n] =
          mfma_bf16(a[m][0], b[n][0], acc[(QA << 2) + m][(QB << 1) + n]);
      acc[(QA << 2) + m][(QB << 1) + n] =
          mfma_bf16(a[m][1], b[n][1], acc[(QA << 2) + m][(QB << 1) + n]);
    }
  __builtin_amdgcn_s_setprio(0);
}

template <int MODE>  // 0 = steady, 1 = u == NT-2, 2 = u == NT-1
DEVI void ktile(u16* lds, int u,
                const u16* gA0, const u16* gA1, const u16* gB0, const u16* gB1,
                const StageCtx& sc,
                const int (&aoff)[4][2], const int (&boff)[2][2],
                short8 (&a0)[4][2], short8 (&a1)[4][2],
                short8 (&b0)[2][2], short8 (&b1)[2][2],
                f32x4 (&acc)[8][4]) {
  const int cs = (u & 1) << 13, ns = ((u + 1) & 1) << 13;
  const u16* A1c = lds + 16384 + cs;
  const u16* B1c = lds + 49152 + cs;
  const size_t uo1 = (size_t)(u + 1) << 6, uo2 = (size_t)(u + 2) << 6;
  // ---- phase 0: MFMA quad(0,0) = a0*b0; issue RB1(u); stage A1(u+1)
  __builtin_amdgcn_s_barrier();
  rdB(B1c, boff, b1);
  if constexpr (MODE <= 1) stage_half(gA1 + uo1, sc, lds + 16384 + ns);
  mmquad<0, 0>(a0, b0, acc);
  // ---- phase 1: MFMA quad(0,1) = a0*b1; issue RA1(u); stage A0(u+2)
  __builtin_amdgcn_s_barrier();
  rdA(A1c, aoff, a1);
  if constexpr (MODE == 0) stage_half(gA0 + uo2, sc, lds + cs);
  mmquad<0, 1>(a0, b1, acc);
  // ---- phase 2: MFMA quad(1,0) = a1*b0; stage B0(u+2); counted vmcnt
  __builtin_amdgcn_s_barrier();
  if constexpr (MODE == 0) stage_half(gB0 + uo2, sc, lds + 32768 + cs);
  mmquad<1, 0>(a1, b0, acc);
  if constexpr (MODE == 0) asm volatile("s_waitcnt vmcnt(4)" ::: "memory");
  if constexpr (MODE == 1) asm volatile("s_waitcnt vmcnt(0)" ::: "memory");
  // ---- phase 3: MFMA quad(1,1) = a1*b1; issue next-tile RA0/RB0; stage B1(u+2)
  __builtin_amdgcn_s_barrier();
  if constexpr (MODE <= 1) {
    rdA(lds + ns, aoff, a0);
    rdB(lds + 32768 + ns, boff, b0);
  }
  if constexpr (MODE == 0) stage_half(gB1 + uo2, sc, lds + 49152 + cs);
  mmquad<1, 1>(a1, b1, acc);
}

template <int FOUT>
DEVI void gemm8p_body(const u16* __restrict__ A, const u16* __restrict__ BT,
                      u16* __restrict__ Cb, float* __restrict__ Cf,
                      int N, int K, int NT, size_t czstride,
                      int ibx, int iby, int ikz) {
  __shared__ __align__(16) u16 lds[65536];   // 128 KiB
  const int tid = threadIdx.x, wave = tid >> 6, lane = tid & 63;
  const int wm = wave >> 2, wn = wave & 3;
  const int fr = lane & 15, fq = (lane >> 4) << 4;   // fq in BYTES
  const long bm = (long)iby << 8, bn = (long)ibx << 8;
  // precomputed swizzled LDS read offsets (u16 units), loop-invariant
  int aoff[4][2], boff[2][2];
#pragma unroll
  for (int m = 0; m < 4; ++m)
#pragma unroll
    for (int ks = 0; ks < 2; ++ks) {
      int row = (wm << 6) + (m << 4) + fr;
      int kb = (ks << 6) + fq;
      aoff[m][ks] = (row << 6) + ((kb ^ ((fr & 7) << 4)) >> 1);
    }
#pragma unroll
  for (int n = 0; n < 2; ++n)
#pragma unroll
    for (int ks = 0; ks < 2; ++ks) {
      int row = (wn << 5) + (n << 4) + fr;
      int kb = (ks << 6) + fq;
      boff[n][ks] = (row << 6) + ((kb ^ ((fr & 7) << 4)) >> 1);
    }
  // stage context: linear LDS dest, inverse-swizzled global source
  StageCtx sc;
#pragma unroll
  for (int s = 0; s < 2; ++s) {
    int c = (s << 9) + tid, row = c >> 3;
    int kbs = (((c & 7) << 4) ^ ((row & 7) << 4));
    sc.go[s] = (size_t)row * K + (kbs >> 1);
    sc.lo[s] = ((s << 9) + (tid & ~63)) << 3;
  }
  const size_t kbase = (size_t)ikz * ((size_t)NT << 6);
  const u16* gA0 = A + (size_t)bm * K + kbase;
  const u16* gA1 = gA0 + (size_t)128 * K;
  const u16* gB0 = BT + (size_t)bn * K + kbase;
  const u16* gB1 = gB0 + (size_t)128 * K;
  f32x4 acc[8][4];
#pragma unroll
  for (int i = 0; i < 8; ++i)
#pragma unroll
    for (int j = 0; j < 4; ++j) acc[i][j] = (f32x4){0.f, 0.f, 0.f, 0.f};
  short8 a0[4][2], a1[4][2], b0[2][2], b1[2][2];
  // prologue: tile 0 all 4 halves, then A0/B0/B1 of tile 1 (A1(1) staged at phi0 of u=0)
  stage_half(gA0, sc, lds + 0);
  stage_half(gA1, sc, lds + 16384);
  stage_half(gB0, sc, lds + 32768);
  stage_half(gB1, sc, lds + 49152);
  stage_half(gA0 + 64, sc, lds + 8192);
  stage_half(gB0 + 64, sc, lds + 32768 + 8192);
  stage_half(gB1 + 64, sc, lds + 49152 + 8192);
  asm volatile("s_waitcnt vmcnt(6)" ::: "memory");   // tile-0's 8 loads landed (own wave)
  __builtin_amdgcn_s_barrier();                      // cross-wave landing
  rdA(lds + 0, aoff, a0);                            // RA0(0)
  rdB(lds + 32768, boff, b0);                        // RB0(0)
  for (int u = 0; u + 2 < NT; ++u)
    ktile<0>(lds, u, gA0, gA1, gB0, gB1, sc, aoff, boff, a0, a1, b0, b1, acc);
  ktile<1>(lds, NT - 2, gA0, gA1, gB0, gB1, sc, aoff, boff, a0, a1, b0, b1, acc);
  ktile<2>(lds, NT - 1, gA0, gA1, gB0, gB1, sc, aoff, boff, a0, a1, b0, b1, acc);
  // epilogue: C/D map col=lane&15 (B side), row=(lane>>4)*4+r (A side)
  const int er = (lane >> 4) << 2, ec = lane & 15;
  float* cf = Cf + (size_t)ikz * czstride;
#pragma unroll
  for (int ai = 0; ai < 8; ++ai) {
    long row0 = bm + ((long)(ai >> 2) << 7) + (wm << 6) + ((ai & 3) << 4) + er;
#pragma unroll
    for (int bj = 0; bj < 4; ++bj) {
      long col = bn + ((long)(bj >> 1) << 7) + (wn << 5) + ((bj & 1) << 4) + ec;
#pragma unroll
      for (int r = 0; r < 4; ++r) {
        if (FOUT) cf[(size_t)(row0 + r) * N + col] = acc[ai][bj][r];
        else      Cb[(size_t)(row0 + r) * N + col] = f2b(acc[ai][bj][r]);
      }
    }
  }
}

// beta = sigmoid(Xb @ WbT^T) computed by the 64 CUs the 192-block QKV grid leaves idle.
// 64 blocks x 32 tokens each; 8 waves split K=2048 into 8x256; LDS-reduce partials.
DEVI void beta_body(const u16* __restrict__ Xb, const u16* __restrict__ WbT,
                    float* __restrict__ beta, int bb) {
  __shared__ float part[8][256];
  int tid = threadIdx.x, w = tid >> 6, lane = tid & 63;
  int fr = lane & 15, fq = (lane >> 4) << 3;
#pragma unroll
  for (int it = 0; it < 2; ++it) {
    int t0 = (bb << 5) + (it << 4);
    const u16* ap = Xb + (size_t)(t0 + fr) * 2048 + (w << 8) + fq;
    const u16* bp = WbT + (size_t)fr * 2048 + (w << 8) + fq;
    f32x4 acc = {0.f, 0.f, 0.f, 0.f};
#pragma unroll
    for (int ks = 0; ks < 8; ++ks)
      acc = mfma_bf16(*(const short8*)(ap + (ks << 5)), *(const short8*)(bp + (ks << 5)), acc);
    int er = (lane >> 4) << 2;
#pragma unroll
    for (int r = 0; r < 4; ++r) part[w][(er + r) * 16 + fr] = acc[r];
    __syncthreads();
    if (tid < 256) {
      float s = 0.f;
#pragma unroll
      for (int j = 0; j < 8; ++j) s += part[j][tid];
      beta[(t0 << 4) + tid] = 1.f / (1.f + __expf(-s));
    }
    __syncthreads();
  }
}

// QKV GEMM (192 blocks) + beta (64 blocks) fused in one 256-block dispatch.
__global__ __launch_bounds__(512, 2)
void k_qkv_beta(const u16* __restrict__ Xb, const u16* __restrict__ WT,
                u16* __restrict__ QKV, const u16* __restrict__ WbT,
                float* __restrict__ beta) {
  int bid = blockIdx.x;
  if (bid < 192)
    gemm8p_body<0>(Xb, WT, QKV, nullptr, 6144, 2048, 32, 0, bid % 24, bid / 24, 0);
  else
    beta_body(Xb, WbT, beta, bid - 192);
}

// Wo GEMM: split-K=4, fp32 partials.
__global__ __launch_bounds__(512, 2)
void k_gemm_wo8p(const u16* __restrict__ A, const u16* __restrict__ BT,
                 float* __restrict__ Cf, int N, int K, int NT, size_t czstride) {
  gemm8p_body<1>(A, BT, nullptr, Cf, N, K, NT, czstride,
                 blockIdx.x, blockIdx.y, blockIdx.z);
}

// ---------------- out = p0+p1+p2+p3 (split-K reduction), float4 ----------------
__global__ __launch_bounds__(256)
void k_add4(const float* __restrict__ p, float* __restrict__ out, size_t stride4) {
  size_t i = (size_t)blockIdx.x * 256 + threadIdx.x;
  const float4* p4 = (const float4*)p;
  float4 a = p4[i], b = p4[i + stride4], c = p4[i + 2 * stride4], d = p4[i + 3 * stride4];
  float4 r;
  r.x = (a.x + b.x) + (c.x + d.x);
  r.y = (a.y + b.y) + (c.y + d.y);
  r.z = (a.z + b.z) + (c.z + d.z);
  r.w = (a.w + b.w) + (c.w + d.w);
  ((float4*)out)[i] = r;
}

// ---------------- causal conv(K=4) + SiLU + l2norm, tile version ----------------
// grid (32, 48): 64-token tile x (kind,head). thread = (token t, 32-d group dg).
__global__ __launch_bounds__(256, 4)
void k_conv(const u16* __restrict__ qkv,
            const float* __restrict__ cwq, const float* __restrict__ cwk,
            const float* __restrict__ cwv,
            u16* __restrict__ qn, u16* __restrict__ kn, u16* __restrict__ vn) {
  __shared__ __align__(16) u16 xs[67 * 136];
  __shared__ float wf[128 * 4];
  int tt = blockIdx.x, s = blockIdx.y;
  int kind = s >> 4, h = s & 15;
  int t0 = tt << 6;
  int col = (kind << 11) + (h << 7);
  int tid = threadIdx.x;
  const float* cw = (kind == 0) ? cwq : ((kind == 1) ? cwk : cwv);
  if (tid < 128) *(float4*)&wf[tid << 2] = *(const float4*)(cw + (size_t)((h << 7) + tid) * 4);
  // stage rows t0-3 .. t0+63 (67 rows x 128 d), coalesced 16B chunks
  for (int i = tid; i < 1072; i += 256) {
    int prow = i >> 4, c8 = (i & 15) << 3;
    int g = t0 - 3 + prow;
    u16x8 v = {0, 0, 0, 0, 0, 0, 0, 0};
    if (g >= 0) v = *(const u16x8*)(qkv + (size_t)g * 6144 + col + c8);
    *(u16x8*)&xs[prow * 136 + c8] = v;
  }
  __syncthreads();
  int t = tid >> 2, dg = tid & 3;
  float y[32];
  float ss = 0.f;
#pragma unroll
  for (int e8 = 0; e8 < 4; ++e8) {
    int d0 = (dg << 5) + (e8 << 3);
    u16x8 a0 = *(const u16x8*)&xs[(t + 0) * 136 + d0];
    u16x8 a1 = *(const u16x8*)&xs[(t + 1) * 136 + d0];
    u16x8 a2 = *(const u16x8*)&xs[(t + 2) * 136 + d0];
    u16x8 a3 = *(const u16x8*)&xs[(t + 3) * 136 + d0];
#pragma unroll
    for (int e = 0; e < 8; ++e) {
      float4 w = *(const float4*)&wf[(d0 + e) << 2];
      float v = b2f(a0[e]) * w.x + b2f(a1[e]) * w.y + b2f(a2[e]) * w.z + b2f(a3[e]) * w.w;
      v = v / (1.f + __expf(-v));   // SiLU
      y[(e8 << 3) + e] = v;
      ss += v * v;
    }
  }
  float sc = 1.f;
  if (kind < 2) {
    ss += __shfl_xor(ss, 1);
    ss += __shfl_xor(ss, 2);
    sc = rsqrtf(ss + 1e-6f);
    if (kind == 0) sc *= 0.08838834764831843f;  // 128^-0.5
  }
  u16* dst = (kind == 0) ? qn : ((kind == 1) ? kn : vn);
  u16* dp = dst + ((size_t)h << 18) + ((size_t)(t0 + t) << 7) + (dg << 5);
#pragma unroll
  for (int e8 = 0; e8 < 4; ++e8) {
    u16x8 p;
#pragma unroll
    for (int e = 0; e < 8; ++e) p[e] = f2b(y[(e8 << 3) + e] * sc);
    *(u16x8*)(dp + (e8 << 3)) = p;
  }
}

// ---------------- per-(chunk,head) parallel prep (v3) ----------------
__global__ __launch_bounds__(256, 2)
void k_prep(const u16* __restrict__ qn, const u16* __restrict__ kn, const u16* __restrict__ vn,
            const float* __restrict__ beta,
            u16* __restrict__ Gg, u16* __restrict__ Wg,
            u16* __restrict__ KTg, u16* __restrict__ UTg) {
  __shared__ __align__(16) char sm[70912];
  u16*  Kc  = (u16*)sm;                 // 64*136*2 = 17408
  u16*  Qc  = (u16*)(sm + 17408);       // 17408 ; overlay: WR
  u16*  Vc  = (u16*)(sm + 34816);       // 17408
  u16*  KTl = (u16*)(sm + 52224);       // 128*72*2 = 18432 ; overlay: AL (64*64*4)
  float* AL = (float*)(sm + 52224);
  float* Bl = (float*)(sm + 70656);     // 256
  u16*  WR  = Qc;
  int h = blockIdx.x, c = blockIdx.y;
  int tid = threadIdx.x, wave = tid >> 6, lane = tid & 63;
  size_t ch = (size_t)(c * 16 + h);
  const u16* kb = kn + ((size_t)h << 18) + ((size_t)c << 13);
  const u16* qb = qn + ((size_t)h << 18) + ((size_t)c << 13);
  const u16* vb = vn + ((size_t)h << 18) + ((size_t)c << 13);
#pragma unroll
  for (int s = 0; s < 4; ++s) {
    int e = (tid + (s << 8)) << 3;
    int t = e >> 7, d = e & 127;
    *(u16x8*)&Kc[t * 136 + d] = *(const u16x8*)(kb + e);
    *(u16x8*)&Qc[t * 136 + d] = *(const u16x8*)(qb + e);
    *(u16x8*)&Vc[t * 136 + d] = *(const u16x8*)(vb + e);
  }
  if (tid < 64) Bl[tid] = beta[((c << 6) + tid) * 16 + h];
  __syncthreads();
  int fr = lane & 15, fq = (lane >> 4) << 3, q4 = (lane >> 4) << 2;
  int arow = (wave << 4) + fr;
  f32x4 kk[4], qk[4];
#pragma unroll
  for (int ct = 0; ct < 4; ++ct) { kk[ct] = (f32x4){0.f,0.f,0.f,0.f}; qk[ct] = (f32x4){0.f,0.f,0.f,0.f}; }
#pragma unroll
  for (int ks = 0; ks < 4; ++ks) {
    short8 aK = *(const short8*)&Kc[arow * 136 + (ks << 5) + fq];
    short8 aQ = *(const short8*)&Qc[arow * 136 + (ks << 5) + fq];
#pragma unroll
    for (int ct = 0; ct < 4; ++ct) {
      short8 bK = *(const short8*)&Kc[((ct << 4) + fr) * 136 + (ks << 5) + fq];
      kk[ct] = mfma_bf16(aK, bK, kk[ct]);
      qk[ct] = mfma_bf16(aQ, bK, qk[ct]);
    }
  }
#pragma unroll
  for (int ct = 0; ct < 4; ++ct)
#pragma unroll
    for (int r = 0; r < 4; ++r) {
      int i = (wave << 4) + q4 + r, j = (ct << 4) + fr;
      Gg[(ch << 12) + i * 64 + j] = f2b((j <= i) ? qk[ct][r] : 0.f);
    }
  // K^T into KTl
  {
    int d = tid & 127, tg = tid >> 7;
#pragma unroll
    for (int it = 0; it < 4; ++it) {
      int t0 = (tg + (it << 1)) << 3;
      u16x8 pk;
#pragma unroll
      for (int j = 0; j < 8; ++j) pk[j] = Kc[(t0 + j) * 136 + d];
      *(u16x8*)&KTl[d * 72 + t0] = pk;
    }
  }
  __syncthreads();
#pragma unroll
  for (int it = 0; it < 4; ++it) {
    int idx = tid + (it << 8);
    int row = idx >> 3, j8 = (idx & 7) << 3;
    *(u16x8*)(KTg + (ch << 13) + (row << 6) + j8) = *(const u16x8*)&KTl[row * 72 + j8];
  }
  __syncthreads();
  {
    float bi[4];
#pragma unroll
    for (int r = 0; r < 4; ++r) bi[r] = Bl[(wave << 4) + q4 + r];
#pragma unroll
    for (int ct = 0; ct < 4; ++ct)
#pragma unroll
      for (int r = 0; r < 4; ++r) {
        int i = (wave << 4) + q4 + r, j = (ct << 4) + fr;
        AL[i * 64 + j] = (j < i) ? bi[r] * kk[ct][r] : 0.f;
      }
  }
  __syncthreads();
  float X[64];
  {
    const u16* colp = (tid < 128) ? (Kc + tid) : (Vc + (tid - 128));
#pragma unroll
    for (int t = 0; t < 64; ++t) X[t] = Bl[t] * b2f(colp[t * 136]);
#pragma unroll
    for (int r = 1; r < 64; ++r) {
      float s = 0.f;
      const float* Ar = &AL[r * 64];
      int r4 = r & ~3;
#pragma unroll
      for (int l = 0; l < 64; l += 4)
        if (l + 4 <= r) {
          float4 a = *(const float4*)(Ar + l);
          s += a.x * X[l] + a.y * X[l + 1] + a.z * X[l + 2] + a.w * X[l + 3];
        }
#pragma unroll
      for (int l = 0; l < 4; ++l)
        if (r4 + l < r) s += Ar[r4 + l] * X[r4 + l];
      X[r] -= s;
    }
  }
  __syncthreads();   // Qc dead -> WR overlay
  if (tid < 128) {
#pragma unroll
    for (int t = 0; t < 64; ++t) WR[t * 136 + tid] = f2b(X[t]);
  } else {
    int v = tid - 128;
    u16* dstr = UTg + (ch << 13) + (v << 6);
#pragma unroll
    for (int j = 0; j < 8; ++j) {
      u16x8 p;
#pragma unroll
      for (int e = 0; e < 8; ++e) p[e] = f2b(X[(j << 3) + e]);
      *(u16x8*)(dstr + (j << 3)) = p;
    }
  }
  __syncthreads();
#pragma unroll
  for (int it = 0; it < 4; ++it) {
    int idx = tid + (it << 8);
    int row = idx >> 4, j8 = (idx & 15) << 3;
    *(u16x8*)(Wg + (ch << 13) + (row << 7) + j8) = *(const u16x8*)&WR[row * 136 + j8];
  }
}

// ---------------- sequential chunked delta-rule scan (lean) ----------------
struct Frags { short8 q[4], w[4], g[2], k[4]; u16x4 u; };

DEVI void load_frags(Frags& f, const u16* qh, const u16* Wg, const u16* Gg,
                     const u16* KTg, const u16* UTg, int c, int h,
                     int trow, int fr, int fq, int q4, int w, int vbase) {
  const u16* qb = qh + ((size_t)((c << 6) + trow + fr) << 7) + fq;
#pragma unroll
  for (int ks = 0; ks < 4; ++ks) f.q[ks] = *(const short8*)(qb + (ks << 5));
  size_t ch = (size_t)(c * 16 + h);
  const u16* wb = Wg + (ch << 13) + ((size_t)(trow + fr) << 7) + fq;
#pragma unroll
  for (int ks = 0; ks < 4; ++ks) f.w[ks] = *(const short8*)(wb + (ks << 5));
  const u16* gb = Gg + (ch << 12) + ((size_t)(trow + fr) << 6) + fq;
#pragma unroll
  for (int ks = 0; ks < 2; ++ks) f.g[ks] = *(const short8*)(gb + (ks << 5));
  const u16* kbp = KTg + (ch << 13) + ((size_t)(w << 5) << 6) + fq;
#pragma unroll
  for (int dt = 0; dt < 2; ++dt)
#pragma unroll
    for (int ks = 0; ks < 2; ++ks)
      f.k[(dt << 1) | ks] = *(const short8*)(kbp + ((size_t)((dt << 4) + fr) << 6) + (ks << 5));
  f.u = *(const u16x4*)(UTg + (ch << 13) + ((size_t)(vbase + fr) << 6) + trow + q4);
}

DEVI void chunk_body(int c, Frags& f, u16* ST, u16* DT, u16* oh,
                     int trow, int fr, int fq, int q4, int w, int vbase,
                     f32x4& S0, f32x4& S1) {
#pragma unroll
  for (int r = 0; r < 4; ++r) {
    ST[(q4 + r) * 136 + (w << 5) + fr] = f2b(S0[r]);
    ST[(q4 + r) * 136 + (w << 5) + 16 + fr] = f2b(S1[r]);
  }
  barrier_lds();
  short8 sf[4];
#pragma unroll
  for (int ks = 0; ks < 4; ++ks) sf[ks] = *(const short8*)&ST[fr * 136 + (ks << 5) + fq];
  f32x4 racc = {0.f,0.f,0.f,0.f}, oacc = {0.f,0.f,0.f,0.f};
#pragma unroll
  for (int ks = 0; ks < 4; ++ks) {
    racc = mfma_bf16(f.w[ks], sf[ks], racc);
    oacc = mfma_bf16(f.q[ks], sf[ks], oacc);
  }
#pragma unroll
  for (int r = 0; r < 4; ++r)
    DT[fr * 72 + trow + q4 + r] = f2b(b2f(f.u[r]) - racc[r]);
  barrier_lds();
  short8 df[2];
#pragma unroll
  for (int ks = 0; ks < 2; ++ks) df[ks] = *(const short8*)&DT[fr * 72 + (ks << 5) + fq];
#pragma unroll
  for (int ks = 0; ks < 2; ++ks) {
    oacc = mfma_bf16(f.g[ks], df[ks], oacc);
    S0 = mfma_bf16(df[ks], f.k[ks], S0);
    S1 = mfma_bf16(df[ks], f.k[2 | ks], S1);
  }
#pragma unroll
  for (int r = 0; r < 4; ++r)
    oh[(size_t)((c << 6) + trow + q4 + r) * 128 + vbase + fr] = f2b(oacc[r]);
}

__global__ __launch_bounds__(256, 1)
void k_delta(const u16* __restrict__ qn, const u16* __restrict__ Wg,
             const u16* __restrict__ Gg, const u16* __restrict__ KTg,
             const u16* __restrict__ UTg, u16* __restrict__ o) {
  __shared__ __align__(16) u16 ST[16 * 136];
  __shared__ __align__(16) u16 DT[16 * 72];
  int bx = blockIdx.x;
  int h = bx & 15, vbase = (bx >> 4) << 4;
  int tid = threadIdx.x, w = tid >> 6, lane = tid & 63;
  int fr = lane & 15, fq = (lane >> 4) << 3, q4 = (lane >> 4) << 2;
  int trow = w << 4;
  const u16* qh = qn + ((size_t)h << 18);
  u16* oh = o + ((size_t)h << 18);
  f32x4 S0 = {0.f,0.f,0.f,0.f}, S1 = {0.f,0.f,0.f,0.f};
  Frags fa, fb;
  load_frags(fa, qh, Wg, Gg, KTg, UTg, 0, h, trow, fr, fq, q4, w, vbase);
  for (int c = 0; c < 32; c += 2) {
    int c1 = c + 1, c2 = (c + 2 < 32) ? c + 2 : 31;
    load_frags(fb, qh, Wg, Gg, KTg, UTg, c1, h, trow, fr, fq, q4, w, vbase);
    chunk_body(c, fa, ST, DT, oh, trow, fr, fq, q4, w, vbase, S0, S1);
    load_frags(fa, qh, Wg, Gg, KTg, UTg, c2, h, trow, fr, fq, q4, w, vbase);
    chunk_body(c1, fb, ST, DT, oh, trow, fr, fq, q4, w, vbase, S0, S1);
  }
}

// ---------------- per-head RMSNorm on o (bf16), tile version ----------------
// grid (32, 16): 64-token tile x head. thread = (token, 32-d group).
__global__ __launch_bounds__(256, 4)
void k_onorm(const u16* __restrict__ o, const float* __restrict__ onw,
             u16* __restrict__ onb) {
  __shared__ float wl[128];
  int tt = blockIdx.x, h = blockIdx.y, tid = threadIdx.x;
  if (tid < 128) wl[tid] = onw[tid];
  __syncthreads();
  int t = tid >> 2, dg = tid & 3;
  const u16* src = o + ((size_t)h << 18) + ((size_t)((tt << 6) + t) << 7) + (dg << 5);
  u16x8 a[4];
  float ss = 0.f;
#pragma unroll
  for (int e8 = 0; e8 < 4; ++e8) {
    a[e8] = *(const u16x8*)(src + (e8 << 3));
#pragma unroll
    for (int e = 0; e < 8; ++e) { float x = b2f(a[e8][e]); ss += x * x; }
  }
  ss += __shfl_xor(ss, 1);
  ss += __shfl_xor(ss, 2);
  float inv = rsqrtf(ss * (1.f / 128.f) + 1e-6f);
  u16* dp = onb + ((size_t)((tt << 6) + t) << 11) + (h << 7) + (dg << 5);
#pragma unroll
  for (int e8 = 0; e8 < 4; ++e8) {
    u16x8 p;
#pragma unroll
    for (int e = 0; e < 8; ++e)
      p[e] = f2b(b2f(a[e8][e]) * inv * wl[(dg << 5) + (e8 << 3) + e]);
    *(u16x8*)(dp + (e8 << 3)) = p;
  }
}

extern "C" void kernel_launch(void* const* d_in, const int* in_sizes, int n_in,
                              void* d_out, int out_size, void* d_ws, size_t ws_size,
                              hipStream_t stream) {
  (void)in_sizes; (void)n_in; (void)out_size; (void)ws_size;
  const float* hs  = (const float*)d_in[0];
  const float* Wq  = (const float*)d_in[1];
  const float* Wk  = (const float*)d_in[2];
  const float* Wv  = (const float*)d_in[3];
  const float* Wb  = (const float*)d_in[4];
  const float* cwq = (const float*)d_in[5];
  const float* cwk = (const float*)d_in[6];
  const float* cwv = (const float*)d_in[7];
  const float* onw = (const float*)d_in[8];
  const float* Wo  = (const float*)d_in[9];
  float* out = (float*)d_out;
  char* ws = (char*)d_ws;
  const size_t MB = 1ull << 20;
  u16*  Xb   = (u16*)(ws);              //  8 MB  hs bf16 [2048][2048]
  u16*  WT   = (u16*)(ws + 8  * MB);    // 24 MB  [Wq|Wk|Wv]^T bf16 [6144][2048]
  u16*  WoT  = (u16*)(ws + 32 * MB);    //  8 MB  Wo^T bf16
  u16*  QKV  = (u16*)(ws + 40 * MB);    // 24 MB  qkv pre-activations (dead after k_conv)
  u16*  Wg   = (u16*)(ws + 40 * MB);    //  8 MB  overlays dead QKV
  u16*  KTg  = (u16*)(ws + 48 * MB);    //  8 MB
  u16*  UTg  = (u16*)(ws + 56 * MB);    //  8 MB
  u16*  qn_  = (u16*)(ws + 64 * MB);    //  8 MB  [16][2048][128]
  u16*  kn_  = (u16*)(ws + 72 * MB);    //  8 MB
  u16*  vn_  = (u16*)(ws + 80 * MB);    //  8 MB
  float* beta= (float*)(ws + 88 * MB);  //  128KB [2048][16]
  u16*  WbT  = (u16*)(ws + 88 * MB + 512 * 1024);  // 64KB [16][2048]
  u16*  Gm   = (u16*)(ws + 89 * MB);    //  4 MB  [32*16][64][64]
  u16*  o_   = (u16*)(ws + 93 * MB);    //  8 MB  bf16 [16][2048][128]
  u16*  onb  = (u16*)(ws + 109 * MB);   //  8 MB  [2048][2048]
  // split-K fp32 partials for the Wo GEMM: 4 x 16 MB contiguous, overlaying regions
  // (Wg/KTg/UTg/qn/kn/vn/Gm/o_) that are all dead once k_onorm has produced onb.
  float* Pk  = (float*)(ws + 40 * MB);  // 64 MB [4][2048][2048]

  k_cvt<<<4224, 256, 0, stream>>>(hs, Xb, 2048 * 2048 / 4, Wb, WbT);
  k_transpose4<<<dim3(32, 32, 4), 256, 0, stream>>>(
      Wq, Wk, Wv, Wo, WT, WT + 2048 * 2048, WT + 2 * 2048 * 2048, WoT);
  k_qkv_beta<<<256, 512, 0, stream>>>(Xb, WT, QKV, WbT, beta);
  k_conv<<<dim3(32, 48), 256, 0, stream>>>(QKV, cwq, cwk, cwv, qn_, kn_, vn_);
  k_prep<<<dim3(16, 32), 256, 0, stream>>>(qn_, kn_, vn_, beta, Gm, Wg, KTg, UTg);
  k_delta<<<128, 256, 0, stream>>>(qn_, Wg, Gm, KTg, UTg, o_);
  k_onorm<<<dim3(32, 16), 256, 0, stream>>>(o_, onw, onb);
  k_gemm_wo8p<<<dim3(8, 8, 4), 512, 0, stream>>>(onb, WoT, Pk, 2048, 2048, 8,
                                                 (size_t)2048 * 2048);
  k_add4<<<4096, 256, 0, stream>>>(Pk, out, (size_t)2048 * 2048 / 4);
}

// Round 5
// 339.046 us; speedup vs baseline: 1.0273x; 1.0273x over previous
//
#include <hip/hip_runtime.h>

typedef unsigned short u16;
typedef __attribute__((ext_vector_type(4))) unsigned short u16x4;
typedef __attribute__((ext_vector_type(8))) unsigned short u16x8;
typedef __attribute__((ext_vector_type(8))) short short8;
typedef __attribute__((ext_vector_type(4))) float f32x4;

#define DEVI __device__ __forceinline__

DEVI u16 f2b(float f) {
  union { float f; unsigned u; } x; x.f = f;
  unsigned r = (x.u + 0x7fffu + ((x.u >> 16) & 1u)) >> 16;
  return (u16)r;
}
DEVI float b2f(u16 h) {
  union { unsigned u; float f; } x; x.u = ((unsigned)h) << 16;
  return x.f;
}
DEVI f32x4 mfma_bf16(short8 a, short8 b, f32x4 c) {
  return __builtin_amdgcn_mfma_f32_16x16x32_bf16(a, b, c, 0, 0, 0);
}
DEVI void gl2lds16(const u16* g, u16* l) {
  __builtin_amdgcn_global_load_lds((__attribute__((address_space(1))) void*)g,
                                   (__attribute__((address_space(3))) void*)l,
                                   16, 0, 0);
}
// barrier that drains only LDS (lgkmcnt), NOT vmcnt -> global prefetch stays in flight
DEVI void barrier_lds() {
  asm volatile("s_waitcnt lgkmcnt(0)\n\ts_barrier" ::: "memory");
}

// ---------------- fp32 -> bf16 convert (hidden_states) + WbT build ----------------
__global__ void k_cvt(const float* __restrict__ src, u16* __restrict__ dst, int n4,
                      const float* __restrict__ Wb, u16* __restrict__ WbT) {
  int b = blockIdx.x;
  if (b < 4096) {
    int i = b * 256 + threadIdx.x;
    if (i < n4) {
      float4 v = ((const float4*)src)[i];
      u16x4 r; r.x = f2b(v.x); r.y = f2b(v.y); r.z = f2b(v.z); r.w = f2b(v.w);
      ((u16x4*)dst)[i] = r;
    }
  } else {
    int j = (b - 4096) * 256 + threadIdx.x;   // 0..32767
    int n = j >> 11, k = j & 2047;
    WbT[j] = f2b(Wb[k * 16 + n]);
  }
}

// ---------------- 4x tiled transpose fp32[2048][2048] -> bf16 transposed ----------------
__global__ __launch_bounds__(256)
void k_transpose4(const float* __restrict__ s0, const float* __restrict__ s1,
                  const float* __restrict__ s2, const float* __restrict__ s3,
                  u16* __restrict__ d0, u16* __restrict__ d1,
                  u16* __restrict__ d2, u16* __restrict__ d3) {
  const int RC = 2048;
  const float* src = (blockIdx.z == 0) ? s0 : (blockIdx.z == 1) ? s1 : (blockIdx.z == 2) ? s2 : s3;
  u16* dst = (blockIdx.z == 0) ? d0 : (blockIdx.z == 1) ? d1 : (blockIdx.z == 2) ? d2 : d3;
  __shared__ u16 tile[64 * 66];
  int bx = blockIdx.x << 6, by = blockIdx.y << 6;
  int x = threadIdx.x & 63, g = threadIdx.x >> 6;
#pragma unroll
  for (int i = 0; i < 16; ++i) {
    int r = (i << 2) + g;
    tile[x * 66 + r] = f2b(src[(size_t)(by + r) * RC + bx + x]);  // transposed into LDS
  }
  __syncthreads();
#pragma unroll
  for (int i = 0; i < 16; ++i) {
    int r = (i << 2) + g;
    dst[(size_t)(bx + r) * RC + by + x] = tile[r * 66 + x];       // 128B coalesced rows
  }
}

// ============ 8-phase 256x256 bf16 MFMA GEMM, ds_reads pipelined one phase ahead ============
// Round-2 schedule (proven 59.9us) + ONE sched_barrier(0) per phase between the read/stage
// issue and the MFMA cluster. Rationale: the next-phase ds_reads are independent of the
// current MFMAs, so the compiler may sink them below the cluster -> their ~576-cyc LDS
// drain lands serially in the next phase's lgkm wait (measured 504 cyc/phase stall).
// Pinning issue-order (reads first) lets the drain hide under the 620-cyc MFMA cluster.
// C[M][N] = A[M][K] @ BT[N][K]^T. BM=BN=256, BK=64, 512 thr = 8 waves (2x4).
// LDS 128 KiB = {A0,A1,B0,B1} x {slot0,slot1} x (128 rows x 64 k) bf16.
// vmcnt(4) at phi2-end proves all four halves of tile u+1 landed before phi3 issues
// next-tile reads. Stage order: phi0->A1(u+1), phi1->A0(u+2), phi2->B0(u+2), phi3->B1(u+2).
// LDS XOR-swizzled reads; inverse swizzle on the per-lane GLOBAL source (rule 21).
// Split-K via ikz. FOUT=0: bf16 out; FOUT=1: fp32 partial to Cf + ikz*czstride.

struct StageCtx { size_t go[2]; int lo[2]; };

DEVI void stage_half(const u16* g, const StageCtx& sc, u16* l) {
  gl2lds16(g + sc.go[0], l + sc.lo[0]);
  gl2lds16(g + sc.go[1], l + sc.lo[1]);
}

DEVI void rdA(const u16* h, const int (&aoff)[4][2], short8 (&a)[4][2]) {
#pragma unroll
  for (int m = 0; m < 4; ++m) {
    a[m][0] = *(const short8*)(h + aoff[m][0]);
    a[m][1] = *(const short8*)(h + aoff[m][1]);
  }
}
DEVI void rdB(const u16* h, const int (&boff)[2][2], short8 (&b)[2][2]) {
#pragma unroll
  for (int n = 0; n < 2; ++n) {
    b[n][0] = *(const short8*)(h + boff[n][0]);
    b[n][1] = *(const short8*)(h + boff[n][1]);
  }
}

template <int QA, int QB>
DEVI void mmquad(const short8 (&a)[4][2], const short8 (&b)[2][2], f32x4 (&acc)[8][4]) {
  __builtin_amdgcn_s_setprio(1);
#pragma unroll
  for (int m = 0; m < 4; ++m)
#pragma unroll
    for (int n = 0; n < 2; ++n) {
      acc[(QA << 2) + m][(QB << 1) + n] =
          mfma_bf16(a[m][0], b[n][0], acc[(QA << 2) + m][(QB << 1) + n]);
      acc[(QA << 2) + m][(QB << 1) + n] =
          mfma_bf16(a[m][1], b[n][1], acc[(QA << 2) + m][(QB << 1) + n]);
    }
  __builtin_amdgcn_s_setprio(0);
}

template <int MODE>  // 0 = steady, 1 = u == NT-2, 2 = u == NT-1
DEVI void ktile(u16* lds, int u,
                const u16* gA0, const u16* gA1, const u16* gB0, const u16* gB1,
                const StageCtx& sc,
                const int (&aoff)[4][2], const int (&boff)[2][2],
                short8 (&a0)[4][2], short8 (&a1)[4][2],
                short8 (&b0)[2][2], short8 (&b1)[2][2],
                f32x4 (&acc)[8][4]) {
  const int cs = (u & 1) << 13, ns = ((u + 1) & 1) << 13;
  const u16* A1c = lds + 16384 + cs;
  const u16* B1c = lds + 49152 + cs;
  const size_t uo1 = (size_t)(u + 1) << 6, uo2 = (size_t)(u + 2) << 6;
  // ---- phase 0: MFMA quad(0,0) = a0*b0; issue RB1(u); stage A1(u+1)
  __builtin_amdgcn_s_barrier();
  rdB(B1c, boff, b1);
  if constexpr (MODE <= 1) stage_half(gA1 + uo1, sc, lds + 16384 + ns);
  __builtin_amdgcn_sched_barrier(0);   // reads/stage issue BEFORE the MFMA cluster
  mmquad<0, 0>(a0, b0, acc);
  // ---- phase 1: MFMA quad(0,1) = a0*b1; issue RA1(u); stage A0(u+2)
  __builtin_amdgcn_s_barrier();
  rdA(A1c, aoff, a1);
  if constexpr (MODE == 0) stage_half(gA0 + uo2, sc, lds + cs);
  __builtin_amdgcn_sched_barrier(0);
  mmquad<0, 1>(a0, b1, acc);
  // ---- phase 2: MFMA quad(1,0) = a1*b0; stage B0(u+2); counted vmcnt
  __builtin_amdgcn_s_barrier();
  if constexpr (MODE == 0) stage_half(gB0 + uo2, sc, lds + 32768 + cs);
  __builtin_amdgcn_sched_barrier(0);
  mmquad<1, 0>(a1, b0, acc);
  if constexpr (MODE == 0) asm volatile("s_waitcnt vmcnt(4)" ::: "memory");
  if constexpr (MODE == 1) asm volatile("s_waitcnt vmcnt(0)" ::: "memory");
  // ---- phase 3: MFMA quad(1,1) = a1*b1; issue next-tile RA0/RB0; stage B1(u+2)
  __builtin_amdgcn_s_barrier();
  if constexpr (MODE <= 1) {
    rdA(lds + ns, aoff, a0);
    rdB(lds + 32768 + ns, boff, b0);
  }
  if constexpr (MODE == 0) stage_half(gB1 + uo2, sc, lds + 49152 + cs);
  __builtin_amdgcn_sched_barrier(0);
  mmquad<1, 1>(a1, b1, acc);
}

template <int FOUT>
DEVI void gemm8p_body(const u16* __restrict__ A, const u16* __restrict__ BT,
                      u16* __restrict__ Cb, float* __restrict__ Cf,
                      int N, int K, int NT, size_t czstride,
                      int ibx, int iby, int ikz) {
  __shared__ __align__(16) u16 lds[65536];   // 128 KiB
  const int tid = threadIdx.x, wave = tid >> 6, lane = tid & 63;
  const int wm = wave >> 2, wn = wave & 3;
  const int fr = lane & 15, fq = (lane >> 4) << 4;   // fq in BYTES
  const long bm = (long)iby << 8, bn = (long)ibx << 8;
  // precomputed swizzled LDS read offsets (u16 units), loop-invariant
  int aoff[4][2], boff[2][2];
#pragma unroll
  for (int m = 0; m < 4; ++m)
#pragma unroll
    for (int ks = 0; ks < 2; ++ks) {
      int row = (wm << 6) + (m << 4) + fr;
      int kb = (ks << 6) + fq;
      aoff[m][ks] = (row << 6) + ((kb ^ ((fr & 7) << 4)) >> 1);
    }
#pragma unroll
  for (int n = 0; n < 2; ++n)
#pragma unroll
    for (int ks = 0; ks < 2; ++ks) {
      int row = (wn << 5) + (n << 4) + fr;
      int kb = (ks << 6) + fq;
      boff[n][ks] = (row << 6) + ((kb ^ ((fr & 7) << 4)) >> 1);
    }
  // stage context: linear LDS dest, inverse-swizzled global source
  StageCtx sc;
#pragma unroll
  for (int s = 0; s < 2; ++s) {
    int c = (s << 9) + tid, row = c >> 3;
    int kbs = (((c & 7) << 4) ^ ((row & 7) << 4));
    sc.go[s] = (size_t)row * K + (kbs >> 1);
    sc.lo[s] = ((s << 9) + (tid & ~63)) << 3;
  }
  const size_t kbase = (size_t)ikz * ((size_t)NT << 6);
  const u16* gA0 = A + (size_t)bm * K + kbase;
  const u16* gA1 = gA0 + (size_t)128 * K;
  const u16* gB0 = BT + (size_t)bn * K + kbase;
  const u16* gB1 = gB0 + (size_t)128 * K;
  f32x4 acc[8][4];
#pragma unroll
  for (int i = 0; i < 8; ++i)
#pragma unroll
    for (int j = 0; j < 4; ++j) acc[i][j] = (f32x4){0.f, 0.f, 0.f, 0.f};
  short8 a0[4][2], a1[4][2], b0[2][2], b1[2][2];
  // prologue: tile 0 all 4 halves, then A0/B0/B1 of tile 1 (A1(1) staged at phi0 of u=0)
  stage_half(gA0, sc, lds + 0);
  stage_half(gA1, sc, lds + 16384);
  stage_half(gB0, sc, lds + 32768);
  stage_half(gB1, sc, lds + 49152);
  stage_half(gA0 + 64, sc, lds + 8192);
  stage_half(gB0 + 64, sc, lds + 32768 + 8192);
  stage_half(gB1 + 64, sc, lds + 49152 + 8192);
  asm volatile("s_waitcnt vmcnt(6)" ::: "memory");   // tile-0's 8 loads landed (own wave)
  __builtin_amdgcn_s_barrier();                      // cross-wave landing
  rdA(lds + 0, aoff, a0);                            // RA0(0)
  rdB(lds + 32768, boff, b0);                        // RB0(0)
  for (int u = 0; u + 2 < NT; ++u)
    ktile<0>(lds, u, gA0, gA1, gB0, gB1, sc, aoff, boff, a0, a1, b0, b1, acc);
  ktile<1>(lds, NT - 2, gA0, gA1, gB0, gB1, sc, aoff, boff, a0, a1, b0, b1, acc);
  ktile<2>(lds, NT - 1, gA0, gA1, gB0, gB1, sc, aoff, boff, a0, a1, b0, b1, acc);
  // epilogue: C/D map col=lane&15 (B side), row=(lane>>4)*4+r (A side)
  const int er = (lane >> 4) << 2, ec = lane & 15;
  float* cf = Cf + (size_t)ikz * czstride;
#pragma unroll
  for (int ai = 0; ai < 8; ++ai) {
    long row0 = bm + ((long)(ai >> 2) << 7) + (wm << 6) + ((ai & 3) << 4) + er;
#pragma unroll
    for (int bj = 0; bj < 4; ++bj) {
      long col = bn + ((long)(bj >> 1) << 7) + (wn << 5) + ((bj & 1) << 4) + ec;
#pragma unroll
      for (int r = 0; r < 4; ++r) {
        if (FOUT) cf[(size_t)(row0 + r) * N + col] = acc[ai][bj][r];
        else      Cb[(size_t)(row0 + r) * N + col] = f2b(acc[ai][bj][r]);
      }
    }
  }
}

// QKV GEMM: 192 blocks (24x8), bf16 out.
__global__ __launch_bounds__(512, 2)
void k_gemm_qkv(const u16* __restrict__ A, const u16* __restrict__ BT,
                u16* __restrict__ Cb) {
  gemm8p_body<0>(A, BT, Cb, nullptr, 6144, 2048, 32, 0,
                 blockIdx.x, blockIdx.y, 0);
}

// Wo GEMM: split-K=4, fp32 partials. 256 blocks (8x8x4), full CU coverage.
__global__ __launch_bounds__(512, 2)
void k_gemm_wo8p(const u16* __restrict__ A, const u16* __restrict__ BT,
                 float* __restrict__ Cf, int N, int K, int NT, size_t czstride) {
  gemm8p_body<1>(A, BT, nullptr, Cf, N, K, NT, czstride,
                 blockIdx.x, blockIdx.y, blockIdx.z);
}

// ---------------- out = p0+p1+p2+p3 (split-K reduction), float4 ----------------
__global__ __launch_bounds__(256)
void k_add4(const float* __restrict__ p, float* __restrict__ out, size_t stride4) {
  size_t i = (size_t)blockIdx.x * 256 + threadIdx.x;
  const float4* p4 = (const float4*)p;
  float4 a = p4[i], b = p4[i + stride4], c = p4[i + 2 * stride4], d = p4[i + 3 * stride4];
  float4 r;
  r.x = (a.x + b.x) + (c.x + d.x);
  r.y = (a.y + b.y) + (c.y + d.y);
  r.z = (a.z + b.z) + (c.z + d.z);
  r.w = (a.w + b.w) + (c.w + d.w);
  ((float4*)out)[i] = r;
}

// ---------------- beta = sigmoid(hs @ Wb) via MFMA ----------------
__global__ __launch_bounds__(256, 4)
void k_beta(const u16* __restrict__ Xb, const u16* __restrict__ WbT,
            float* __restrict__ beta) {
  __shared__ float part[4][256];
  int tid = threadIdx.x, w = tid >> 6, lane = tid & 63;
  int t0 = blockIdx.x << 4;
  int fr = lane & 15, fq = (lane >> 4) << 3;
  const u16* ap = Xb + (size_t)(t0 + fr) * 2048 + (w << 9) + fq;
  const u16* bp = WbT + (size_t)fr * 2048 + (w << 9) + fq;
  f32x4 acc = {0.f, 0.f, 0.f, 0.f};
#pragma unroll
  for (int ks = 0; ks < 16; ++ks)
    acc = mfma_bf16(*(const short8*)(ap + (ks << 5)), *(const short8*)(bp + (ks << 5)), acc);
  int er = (lane >> 4) << 2;
#pragma unroll
  for (int r = 0; r < 4; ++r) part[w][(er + r) * 16 + fr] = acc[r];
  __syncthreads();
  float s = part[0][tid] + part[1][tid] + part[2][tid] + part[3][tid];
  beta[(t0 << 4) + tid] = 1.f / (1.f + __expf(-s));
}

// ---------------- causal conv(K=4) + SiLU + l2norm, tile version ----------------
// grid (32, 48): 64-token tile x (kind,head). thread = (token t, 32-d group dg).
__global__ __launch_bounds__(256, 4)
void k_conv(const u16* __restrict__ qkv,
            const float* __restrict__ cwq, const float* __restrict__ cwk,
            const float* __restrict__ cwv,
            u16* __restrict__ qn, u16* __restrict__ kn, u16* __restrict__ vn) {
  __shared__ __align__(16) u16 xs[67 * 136];
  __shared__ float wf[128 * 4];
  int tt = blockIdx.x, s = blockIdx.y;
  int kind = s >> 4, h = s & 15;
  int t0 = tt << 6;
  int col = (kind << 11) + (h << 7);
  int tid = threadIdx.x;
  const float* cw = (kind == 0) ? cwq : ((kind == 1) ? cwk : cwv);
  if (tid < 128) *(float4*)&wf[tid << 2] = *(const float4*)(cw + (size_t)((h << 7) + tid) * 4);
  // stage rows t0-3 .. t0+63 (67 rows x 128 d), coalesced 16B chunks
  for (int i = tid; i < 1072; i += 256) {
    int prow = i >> 4, c8 = (i & 15) << 3;
    int g = t0 - 3 + prow;
    u16x8 v = {0, 0, 0, 0, 0, 0, 0, 0};
    if (g >= 0) v = *(const u16x8*)(qkv + (size_t)g * 6144 + col + c8);
    *(u16x8*)&xs[prow * 136 + c8] = v;
  }
  __syncthreads();
  int t = tid >> 2, dg = tid & 3;
  float y[32];
  float ss = 0.f;
#pragma unroll
  for (int e8 = 0; e8 < 4; ++e8) {
    int d0 = (dg << 5) + (e8 << 3);
    u16x8 a0 = *(const u16x8*)&xs[(t + 0) * 136 + d0];
    u16x8 a1 = *(const u16x8*)&xs[(t + 1) * 136 + d0];
    u16x8 a2 = *(const u16x8*)&xs[(t + 2) * 136 + d0];
    u16x8 a3 = *(const u16x8*)&xs[(t + 3) * 136 + d0];
#pragma unroll
    for (int e = 0; e < 8; ++e) {
      float4 w = *(const float4*)&wf[(d0 + e) << 2];
      float v = b2f(a0[e]) * w.x + b2f(a1[e]) * w.y + b2f(a2[e]) * w.z + b2f(a3[e]) * w.w;
      v = v / (1.f + __expf(-v));   // SiLU
      y[(e8 << 3) + e] = v;
      ss += v * v;
    }
  }
  float sc = 1.f;
  if (kind < 2) {
    ss += __shfl_xor(ss, 1);
    ss += __shfl_xor(ss, 2);
    sc = rsqrtf(ss + 1e-6f);
    if (kind == 0) sc *= 0.08838834764831843f;  // 128^-0.5
  }
  u16* dst = (kind == 0) ? qn : ((kind == 1) ? kn : vn);
  u16* dp = dst + ((size_t)h << 18) + ((size_t)(t0 + t) << 7) + (dg << 5);
#pragma unroll
  for (int e8 = 0; e8 < 4; ++e8) {
    u16x8 p;
#pragma unroll
    for (int e = 0; e < 8; ++e) p[e] = f2b(y[(e8 << 3) + e] * sc);
    *(u16x8*)(dp + (e8 << 3)) = p;
  }
}

// ---------------- per-(chunk,head) parallel prep (v3) ----------------
__global__ __launch_bounds__(256, 2)
void k_prep(const u16* __restrict__ qn, const u16* __restrict__ kn, const u16* __restrict__ vn,
            const float* __restrict__ beta,
            u16* __restrict__ Gg, u16* __restrict__ Wg,
            u16* __restrict__ KTg, u16* __restrict__ UTg) {
  __shared__ __align__(16) char sm[70912];
  u16*  Kc  = (u16*)sm;                 // 64*136*2 = 17408
  u16*  Qc  = (u16*)(sm + 17408);       // 17408 ; overlay: WR
  u16*  Vc  = (u16*)(sm + 34816);       // 17408
  u16*  KTl = (u16*)(sm + 52224);       // 128*72*2 = 18432 ; overlay: AL (64*64*4)
  float* AL = (float*)(sm + 52224);
  float* Bl = (float*)(sm + 70656);     // 256
  u16*  WR  = Qc;
  int h = blockIdx.x, c = blockIdx.y;
  int tid = threadIdx.x, wave = tid >> 6, lane = tid & 63;
  size_t ch = (size_t)(c * 16 + h);
  const u16* kb = kn + ((size_t)h << 18) + ((size_t)c << 13);
  const u16* qb = qn + ((size_t)h << 18) + ((size_t)c << 13);
  const u16* vb = vn + ((size_t)h << 18) + ((size_t)c << 13);
#pragma unroll
  for (int s = 0; s < 4; ++s) {
    int e = (tid + (s << 8)) << 3;
    int t = e >> 7, d = e & 127;
    *(u16x8*)&Kc[t * 136 + d] = *(const u16x8*)(kb + e);
    *(u16x8*)&Qc[t * 136 + d] = *(const u16x8*)(qb + e);
    *(u16x8*)&Vc[t * 136 + d] = *(const u16x8*)(vb + e);
  }
  if (tid < 64) Bl[tid] = beta[((c << 6) + tid) * 16 + h];
  __syncthreads();
  int fr = lane & 15, fq = (lane >> 4) << 3, q4 = (lane >> 4) << 2;
  int arow = (wave << 4) + fr;
  f32x4 kk[4], qk[4];
#pragma unroll
  for (int ct = 0; ct < 4; ++ct) { kk[ct] = (f32x4){0.f,0.f,0.f,0.f}; qk[ct] = (f32x4){0.f,0.f,0.f,0.f}; }
#pragma unroll
  for (int ks = 0; ks < 4; ++ks) {
    short8 aK = *(const short8*)&Kc[arow * 136 + (ks << 5) + fq];
    short8 aQ = *(const short8*)&Qc[arow * 136 + (ks << 5) + fq];
#pragma unroll
    for (int ct = 0; ct < 4; ++ct) {
      short8 bK = *(const short8*)&Kc[((ct << 4) + fr) * 136 + (ks << 5) + fq];
      kk[ct] = mfma_bf16(aK, bK, kk[ct]);
      qk[ct] = mfma_bf16(aQ, bK, qk[ct]);
    }
  }
#pragma unroll
  for (int ct = 0; ct < 4; ++ct)
#pragma unroll
    for (int r = 0; r < 4; ++r) {
      int i = (wave << 4) + q4 + r, j = (ct << 4) + fr;
      Gg[(ch << 12) + i * 64 + j] = f2b((j <= i) ? qk[ct][r] : 0.f);
    }
  // K^T into KTl
  {
    int d = tid & 127, tg = tid >> 7;
#pragma unroll
    for (int it = 0; it < 4; ++it) {
      int t0 = (tg + (it << 1)) << 3;
      u16x8 pk;
#pragma unroll
      for (int j = 0; j < 8; ++j) pk[j] = Kc[(t0 + j) * 136 + d];
      *(u16x8*)&KTl[d * 72 + t0] = pk;
    }
  }
  __syncthreads();
#pragma unroll
  for (int it = 0; it < 4; ++it) {
    int idx = tid + (it << 8);
    int row = idx >> 3, j8 = (idx & 7) << 3;
    *(u16x8*)(KTg + (ch << 13) + (row << 6) + j8) = *(const u16x8*)&KTl[row * 72 + j8];
  }
  __syncthreads();
  {
    float bi[4];
#pragma unroll
    for (int r = 0; r < 4; ++r) bi[r] = Bl[(wave << 4) + q4 + r];
#pragma unroll
    for (int ct = 0; ct < 4; ++ct)
#pragma unroll
      for (int r = 0; r < 4; ++r) {
        int i = (wave << 4) + q4 + r, j = (ct << 4) + fr;
        AL[i * 64 + j] = (j < i) ? bi[r] * kk[ct][r] : 0.f;
      }
  }
  __syncthreads();
  float X[64];
  {
    const u16* colp = (tid < 128) ? (Kc + tid) : (Vc + (tid - 128));
#pragma unroll
    for (int t = 0; t < 64; ++t) X[t] = Bl[t] * b2f(colp[t * 136]);
#pragma unroll
    for (int r = 1; r < 64; ++r) {
      float s = 0.f;
      const float* Ar = &AL[r * 64];
      int r4 = r & ~3;
#pragma unroll
      for (int l = 0; l < 64; l += 4)
        if (l + 4 <= r) {
          float4 a = *(const float4*)(Ar + l);
          s += a.x * X[l] + a.y * X[l + 1] + a.z * X[l + 2] + a.w * X[l + 3];
        }
#pragma unroll
      for (int l = 0; l < 4; ++l)
        if (r4 + l < r) s += Ar[r4 + l] * X[r4 + l];
      X[r] -= s;
    }
  }
  __syncthreads();   // Qc dead -> WR overlay
  if (tid < 128) {
#pragma unroll
    for (int t = 0; t < 64; ++t) WR[t * 136 + tid] = f2b(X[t]);
  } else {
    int v = tid - 128;
    u16* dstr = UTg + (ch << 13) + (v << 6);
#pragma unroll
    for (int j = 0; j < 8; ++j) {
      u16x8 p;
#pragma unroll
      for (int e = 0; e < 8; ++e) p[e] = f2b(X[(j << 3) + e]);
      *(u16x8*)(dstr + (j << 3)) = p;
    }
  }
  __syncthreads();
#pragma unroll
  for (int it = 0; it < 4; ++it) {
    int idx = tid + (it << 8);
    int row = idx >> 4, j8 = (idx & 15) << 3;
    *(u16x8*)(Wg + (ch << 13) + (row << 7) + j8) = *(const u16x8*)&WR[row * 136 + j8];
  }
}

// ---------------- sequential chunked delta-rule scan (lean) ----------------
struct Frags { short8 q[4], w[4], g[2], k[4]; u16x4 u; };

DEVI void load_frags(Frags& f, const u16* qh, const u16* Wg, const u16* Gg,
                     const u16* KTg, const u16* UTg, int c, int h,
                     int trow, int fr, int fq, int q4, int w, int vbase) {
  const u16* qb = qh + ((size_t)((c << 6) + trow + fr) << 7) + fq;
#pragma unroll
  for (int ks = 0; ks < 4; ++ks) f.q[ks] = *(const short8*)(qb + (ks << 5));
  size_t ch = (size_t)(c * 16 + h);
  const u16* wb = Wg + (ch << 13) + ((size_t)(trow + fr) << 7) + fq;
#pragma unroll
  for (int ks = 0; ks < 4; ++ks) f.w[ks] = *(const short8*)(wb + (ks << 5));
  const u16* gb = Gg + (ch << 12) + ((size_t)(trow + fr) << 6) + fq;
#pragma unroll
  for (int ks = 0; ks < 2; ++ks) f.g[ks] = *(const short8*)(gb + (ks << 5));
  const u16* kbp = KTg + (ch << 13) + ((size_t)(w << 5) << 6) + fq;
#pragma unroll
  for (int dt = 0; dt < 2; ++dt)
#pragma unroll
    for (int ks = 0; ks < 2; ++ks)
      f.k[(dt << 1) | ks] = *(const short8*)(kbp + ((size_t)((dt << 4) + fr) << 6) + (ks << 5));
  f.u = *(const u16x4*)(UTg + (ch << 13) + ((size_t)(vbase + fr) << 6) + trow + q4);
}

DEVI void chunk_body(int c, Frags& f, u16* ST, u16* DT, u16* oh,
                     int trow, int fr, int fq, int q4, int w, int vbase,
                     f32x4& S0, f32x4& S1) {
#pragma unroll
  for (int r = 0; r < 4; ++r) {
    ST[(q4 + r) * 136 + (w << 5) + fr] = f2b(S0[r]);
    ST[(q4 + r) * 136 + (w << 5) + 16 + fr] = f2b(S1[r]);
  }
  barrier_lds();
  short8 sf[4];
#pragma unroll
  for (int ks = 0; ks < 4; ++ks) sf[ks] = *(const short8*)&ST[fr * 136 + (ks << 5) + fq];
  f32x4 racc = {0.f,0.f,0.f,0.f}, oacc = {0.f,0.f,0.f,0.f};
#pragma unroll
  for (int ks = 0; ks < 4; ++ks) {
    racc = mfma_bf16(f.w[ks], sf[ks], racc);
    oacc = mfma_bf16(f.q[ks], sf[ks], oacc);
  }
#pragma unroll
  for (int r = 0; r < 4; ++r)
    DT[fr * 72 + trow + q4 + r] = f2b(b2f(f.u[r]) - racc[r]);
  barrier_lds();
  short8 df[2];
#pragma unroll
  for (int ks = 0; ks < 2; ++ks) df[ks] = *(const short8*)&DT[fr * 72 + (ks << 5) + fq];
#pragma unroll
  for (int ks = 0; ks < 2; ++ks) {
    oacc = mfma_bf16(f.g[ks], df[ks], oacc);
    S0 = mfma_bf16(df[ks], f.k[ks], S0);
    S1 = mfma_bf16(df[ks], f.k[2 | ks], S1);
  }
#pragma unroll
  for (int r = 0; r < 4; ++r)
    oh[(size_t)((c << 6) + trow + q4 + r) * 128 + vbase + fr] = f2b(oacc[r]);
}

__global__ __launch_bounds__(256, 1)
void k_delta(const u16* __restrict__ qn, const u16* __restrict__ Wg,
             const u16* __restrict__ Gg, const u16* __restrict__ KTg,
             const u16* __restrict__ UTg, u16* __restrict__ o) {
  __shared__ __align__(16) u16 ST[16 * 136];
  __shared__ __align__(16) u16 DT[16 * 72];
  int bx = blockIdx.x;
  int h = bx & 15, vbase = (bx >> 4) << 4;
  int tid = threadIdx.x, w = tid >> 6, lane = tid & 63;
  int fr = lane & 15, fq = (lane >> 4) << 3, q4 = (lane >> 4) << 2;
  int trow = w << 4;
  const u16* qh = qn + ((size_t)h << 18);
  u16* oh = o + ((size_t)h << 18);
  f32x4 S0 = {0.f,0.f,0.f,0.f}, S1 = {0.f,0.f,0.f,0.f};
  Frags fa, fb;
  load_frags(fa, qh, Wg, Gg, KTg, UTg, 0, h, trow, fr, fq, q4, w, vbase);
  for (int c = 0; c < 32; c += 2) {
    int c1 = c + 1, c2 = (c + 2 < 32) ? c + 2 : 31;
    load_frags(fb, qh, Wg, Gg, KTg, UTg, c1, h, trow, fr, fq, q4, w, vbase);
    chunk_body(c, fa, ST, DT, oh, trow, fr, fq, q4, w, vbase, S0, S1);
    load_frags(fa, qh, Wg, Gg, KTg, UTg, c2, h, trow, fr, fq, q4, w, vbase);
    chunk_body(c1, fb, ST, DT, oh, trow, fr, fq, q4, w, vbase, S0, S1);
  }
}

// ---------------- per-head RMSNorm on o (bf16), tile version ----------------
// grid (32, 16): 64-token tile x head. thread = (token, 32-d group).
__global__ __launch_bounds__(256, 4)
void k_onorm(const u16* __restrict__ o, const float* __restrict__ onw,
             u16* __restrict__ onb) {
  __shared__ float wl[128];
  int tt = blockIdx.x, h = blockIdx.y, tid = threadIdx.x;
  if (tid < 128) wl[tid] = onw[tid];
  __syncthreads();
  int t = tid >> 2, dg = tid & 3;
  const u16* src = o + ((size_t)h << 18) + ((size_t)((tt << 6) + t) << 7) + (dg << 5);
  u16x8 a[4];
  float ss = 0.f;
#pragma unroll
  for (int e8 = 0; e8 < 4; ++e8) {
    a[e8] = *(const u16x8*)(src + (e8 << 3));
#pragma unroll
    for (int e = 0; e < 8; ++e) { float x = b2f(a[e8][e]); ss += x * x; }
  }
  ss += __shfl_xor(ss, 1);
  ss += __shfl_xor(ss, 2);
  float inv = rsqrtf(ss * (1.f / 128.f) + 1e-6f);
  u16* dp = onb + ((size_t)((tt << 6) + t) << 11) + (h << 7) + (dg << 5);
#pragma unroll
  for (int e8 = 0; e8 < 4; ++e8) {
    u16x8 p;
#pragma unroll
    for (int e = 0; e < 8; ++e)
      p[e] = f2b(b2f(a[e8][e]) * inv * wl[(dg << 5) + (e8 << 3) + e]);
    *(u16x8*)(dp + (e8 << 3)) = p;
  }
}

extern "C" void kernel_launch(void* const* d_in, const int* in_sizes, int n_in,
                              void* d_out, int out_size, void* d_ws, size_t ws_size,
                              hipStream_t stream) {
  (void)in_sizes; (void)n_in; (void)out_size; (void)ws_size;
  const float* hs  = (const float*)d_in[0];
  const float* Wq  = (const float*)d_in[1];
  const float* Wk  = (const float*)d_in[2];
  const float* Wv  = (const float*)d_in[3];
  const float* Wb  = (const float*)d_in[4];
  const float* cwq = (const float*)d_in[5];
  const float* cwk = (const float*)d_in[6];
  const float* cwv = (const float*)d_in[7];
  const float* onw = (const float*)d_in[8];
  const float* Wo  = (const float*)d_in[9];
  float* out = (float*)d_out;
  char* ws = (char*)d_ws;
  const size_t MB = 1ull << 20;
  u16*  Xb   = (u16*)(ws);              //  8 MB  hs bf16 [2048][2048]
  u16*  WT   = (u16*)(ws + 8  * MB);    // 24 MB  [Wq|Wk|Wv]^T bf16 [6144][2048]
  u16*  WoT  = (u16*)(ws + 32 * MB);    //  8 MB  Wo^T bf16
  u16*  QKV  = (u16*)(ws + 40 * MB);    // 24 MB  qkv pre-activations (dead after k_conv)
  u16*  Wg   = (u16*)(ws + 40 * MB);    //  8 MB  overlays dead QKV
  u16*  KTg  = (u16*)(ws + 48 * MB);    //  8 MB
  u16*  UTg  = (u16*)(ws + 56 * MB);    //  8 MB
  u16*  qn_  = (u16*)(ws + 64 * MB);    //  8 MB  [16][2048][128]
  u16*  kn_  = (u16*)(ws + 72 * MB);    //  8 MB
  u16*  vn_  = (u16*)(ws + 80 * MB);    //  8 MB
  float* beta= (float*)(ws + 88 * MB);  //  128KB [2048][16]
  u16*  WbT  = (u16*)(ws + 88 * MB + 512 * 1024);  // 64KB [16][2048]
  u16*  Gm   = (u16*)(ws + 89 * MB);    //  4 MB  [32*16][64][64]
  u16*  o_   = (u16*)(ws + 93 * MB);    //  8 MB  bf16 [16][2048][128]
  u16*  onb  = (u16*)(ws + 109 * MB);   //  8 MB  [2048][2048]
  // split-K fp32 partials for the Wo GEMM: 4 x 16 MB contiguous, overlaying regions
  // (Wg/KTg/UTg/qn/kn/vn/Gm/o_) that are all dead once k_onorm has produced onb.
  float* Pk  = (float*)(ws + 40 * MB);  // 64 MB [4][2048][2048]

  k_cvt<<<4224, 256, 0, stream>>>(hs, Xb, 2048 * 2048 / 4, Wb, WbT);
  k_transpose4<<<dim3(32, 32, 4), 256, 0, stream>>>(
      Wq, Wk, Wv, Wo, WT, WT + 2048 * 2048, WT + 2 * 2048 * 2048, WoT);
  k_gemm_qkv<<<dim3(24, 8), 512, 0, stream>>>(Xb, WT, QKV);
  k_beta<<<128, 256, 0, stream>>>(Xb, WbT, beta);
  k_conv<<<dim3(32, 48), 256, 0, stream>>>(QKV, cwq, cwk, cwv, qn_, kn_, vn_);
  k_prep<<<dim3(16, 32), 256, 0, stream>>>(qn_, kn_, vn_, beta, Gm, Wg, KTg, UTg);
  k_delta<<<128, 256, 0, stream>>>(qn_, Wg, Gm, KTg, UTg, o_);
  k_onorm<<<dim3(32, 16), 256, 0, stream>>>(o_, onw, onb);
  k_gemm_wo8p<<<dim3(8, 8, 4), 512, 0, stream>>>(onb, WoT, Pk, 2048, 2048, 8,
                                                 (size_t)2048 * 2048);
  k_add4<<<4096, 256, 0, stream>>>(Pk, out, (size_t)2048 * 2048 / 4);
}

// Round 7
// 332.078 us; speedup vs baseline: 1.0488x; 1.0210x over previous
//
#include <hip/hip_runtime.h>

typedef unsigned short u16;
typedef __attribute__((ext_vector_type(4))) unsigned short u16x4;
typedef __attribute__((ext_vector_type(8))) unsigned short u16x8;
typedef __attribute__((ext_vector_type(8))) short short8;
typedef __attribute__((ext_vector_type(4))) float f32x4;

#define DEVI __device__ __forceinline__

DEVI u16 f2b(float f) {
  union { float f; unsigned u; } x; x.f = f;
  unsigned r = (x.u + 0x7fffu + ((x.u >> 16) & 1u)) >> 16;
  return (u16)r;
}
DEVI float b2f(u16 h) {
  union { unsigned u; float f; } x; x.u = ((unsigned)h) << 16;
  return x.f;
}
DEVI f32x4 mfma_bf16(short8 a, short8 b, f32x4 c) {
  return __builtin_amdgcn_mfma_f32_16x16x32_bf16(a, b, c, 0, 0, 0);
}
DEVI void gl2lds16(const u16* g, u16* l) {
  __builtin_amdgcn_global_load_lds((__attribute__((address_space(1))) void*)g,
                                   (__attribute__((address_space(3))) void*)l,
                                   16, 0, 0);
}
// barrier that drains only LDS (lgkmcnt), NOT vmcnt -> global prefetch stays in flight
DEVI void barrier_lds() {
  asm volatile("s_waitcnt lgkmcnt(0)\n\ts_barrier" ::: "memory");
}

// ---- fused input prep: fp32->bf16 cvt (hs) + WbT build + 4x 64x64-tile transpose ----
// blocks [0,4096): hs cvt; [4096,4224): WbT; [4224,8320): transposes of Wq/Wk/Wv/Wo.
__global__ __launch_bounds__(256)
void k_pre(const float* __restrict__ hs, u16* __restrict__ Xb,
           const float* __restrict__ Wb, u16* __restrict__ WbT,
           const float* __restrict__ Wq, const float* __restrict__ Wk,
           const float* __restrict__ Wv, const float* __restrict__ Wo,
           u16* __restrict__ WT, u16* __restrict__ WoT) {
  __shared__ u16 tile[64 * 66];
  int b = blockIdx.x;
  if (b < 4096) {
    int i = b * 256 + threadIdx.x;
    float4 v = ((const float4*)hs)[i];
    u16x4 r; r.x = f2b(v.x); r.y = f2b(v.y); r.z = f2b(v.z); r.w = f2b(v.w);
    ((u16x4*)Xb)[i] = r;
    return;
  }
  if (b < 4224) {
    int j = (b - 4096) * 256 + threadIdx.x;   // 0..32767
    int n = j >> 11, k = j & 2047;
    WbT[j] = f2b(Wb[k * 16 + n]);
    return;
  }
  const int RC = 2048;
  int tb = b - 4224;                  // 0..4095
  int z = tb >> 10, t = tb & 1023;
  const float* src = (z == 0) ? Wq : (z == 1) ? Wk : (z == 2) ? Wv : Wo;
  u16* dst = (z == 0) ? WT : (z == 1) ? (WT + 2048 * 2048)
           : (z == 2) ? (WT + 2 * 2048 * 2048) : WoT;
  int bx = (t & 31) << 6, by = (t >> 5) << 6;
  int x = threadIdx.x & 63, g = threadIdx.x >> 6;
#pragma unroll
  for (int i = 0; i < 16; ++i) {
    int r = (i << 2) + g;
    tile[x * 66 + r] = f2b(src[(size_t)(by + r) * RC + bx + x]);  // transposed into LDS
  }
  __syncthreads();
#pragma unroll
  for (int i = 0; i < 16; ++i) {
    int r = (i << 2) + g;
    dst[(size_t)(bx + r) * RC + by + x] = tile[r * 66 + x];       // 128B coalesced rows
  }
}

// ============ 8-phase 256x256 bf16 MFMA GEMM, ds_reads pipelined one phase ahead ============
// (round-2 schedule — measured best at 59.9us. 1 barrier/phase, reads issued one phase
//  before use, compiler emits counted lgkmcnt. sched_barrier pinning tested: neutral;
//  m201-style 2-barrier + lgkmcnt(0): regression. Do not re-add without new evidence.)
// C[M][N] = A[M][K] @ BT[N][K]^T. BM=BN=256, BK=64, 512 thr = 8 waves (2x4).
// LDS 128 KiB = {A0,A1,B0,B1} x {slot0,slot1} x (128 rows x 64 k) bf16.
// vmcnt(4) at phi2-end proves all four halves of tile u+1 landed before phi3 issues
// next-tile reads. Stage order: phi0->A1(u+1), phi1->A0(u+2), phi2->B0(u+2), phi3->B1(u+2).
// LDS XOR-swizzled reads; inverse swizzle on the per-lane GLOBAL source (rule 21).
// Grid note: (24,8) keeps each B-panel's 8 consumer blocks on ONE XCD (24%8==0) — B
// is already XCD-local; A-localizing swap is worse (200MB vs 88MB L2-fill). No swizzle.

struct StageCtx { size_t go[2]; int lo[2]; };

DEVI void stage_half(const u16* g, const StageCtx& sc, u16* l) {
  gl2lds16(g + sc.go[0], l + sc.lo[0]);
  gl2lds16(g + sc.go[1], l + sc.lo[1]);
}

DEVI void rdA(const u16* h, const int (&aoff)[4][2], short8 (&a)[4][2]) {
#pragma unroll
  for (int m = 0; m < 4; ++m) {
    a[m][0] = *(const short8*)(h + aoff[m][0]);
    a[m][1] = *(const short8*)(h + aoff[m][1]);
  }
}
DEVI void rdB(const u16* h, const int (&boff)[2][2], short8 (&b)[2][2]) {
#pragma unroll
  for (int n = 0; n < 2; ++n) {
    b[n][0] = *(const short8*)(h + boff[n][0]);
    b[n][1] = *(const short8*)(h + boff[n][1]);
  }
}

template <int QA, int QB>
DEVI void mmquad(const short8 (&a)[4][2], const short8 (&b)[2][2], f32x4 (&acc)[8][4]) {
  __builtin_amdgcn_s_setprio(1);
#pragma unroll
  for (int m = 0; m < 4; ++m)
#pragma unroll
    for (int n = 0; n < 2; ++n) {
      acc[(QA << 2) + m][(QB << 1) + n] =
          mfma_bf16(a[m][0], b[n][0], acc[(QA << 2) + m][(QB << 1) + n]);
      acc[(QA << 2) + m][(QB << 1) + n] =
          mfma_bf16(a[m][1], b[n][1], acc[(QA << 2) + m][(QB << 1) + n]);
    }
  __builtin_amdgcn_s_setprio(0);
}

template <int MODE>  // 0 = steady, 1 = u == NT-2, 2 = u == NT-1
DEVI void ktile(u16* lds, int u,
                const u16* gA0, const u16* gA1, const u16* gB0, const u16* gB1,
                const StageCtx& sc,
                const int (&aoff)[4][2], const int (&boff)[2][2],
                short8 (&a0)[4][2], short8 (&a1)[4][2],
                short8 (&b0)[2][2], short8 (&b1)[2][2],
                f32x4 (&acc)[8][4]) {
  const int cs = (u & 1) << 13, ns = ((u + 1) & 1) << 13;
  const u16* A1c = lds + 16384 + cs;
  const u16* B1c = lds + 49152 + cs;
  const size_t uo1 = (size_t)(u + 1) << 6, uo2 = (size_t)(u + 2) << 6;
  // ---- phase 0: MFMA quad(0,0) = a0*b0; issue RB1(u); stage A1(u+1)
  __builtin_amdgcn_s_barrier();
  rdB(B1c, boff, b1);
  if constexpr (MODE <= 1) stage_half(gA1 + uo1, sc, lds + 16384 + ns);
  mmquad<0, 0>(a0, b0, acc);
  // ---- phase 1: MFMA quad(0,1) = a0*b1; issue RA1(u); stage A0(u+2)
  __builtin_amdgcn_s_barrier();
  rdA(A1c, aoff, a1);
  if constexpr (MODE == 0) stage_half(gA0 + uo2, sc, lds + cs);
  mmquad<0, 1>(a0, b1, acc);
  // ---- phase 2: MFMA quad(1,0) = a1*b0; stage B0(u+2); counted vmcnt
  __builtin_amdgcn_s_barrier();
  if constexpr (MODE == 0) stage_half(gB0 + uo2, sc, lds + 32768 + cs);
  mmquad<1, 0>(a1, b0, acc);
  if constexpr (MODE == 0) asm volatile("s_waitcnt vmcnt(4)" ::: "memory");
  if constexpr (MODE == 1) asm volatile("s_waitcnt vmcnt(0)" ::: "memory");
  // ---- phase 3: MFMA quad(1,1) = a1*b1; issue next-tile RA0/RB0; stage B1(u+2)
  __builtin_amdgcn_s_barrier();
  if constexpr (MODE <= 1) {
    rdA(lds + ns, aoff, a0);
    rdB(lds + 32768 + ns, boff, b0);
  }
  if constexpr (MODE == 0) stage_half(gB1 + uo2, sc, lds + 49152 + cs);
  mmquad<1, 1>(a1, b1, acc);
}

__global__ __launch_bounds__(512, 2)
void k_gemm8p(const u16* __restrict__ A, const u16* __restrict__ BT,
              u16* __restrict__ Cb, int N, int K) {
  __shared__ __align__(16) u16 lds[65536];   // 128 KiB
  const int tid = threadIdx.x, wave = tid >> 6, lane = tid & 63;
  const int wm = wave >> 2, wn = wave & 3;
  const int fr = lane & 15, fq = (lane >> 4) << 4;   // fq in BYTES
  const long bm = (long)blockIdx.y << 8, bn = (long)blockIdx.x << 8;
  const int NT = K >> 6;
  // precomputed swizzled LDS read offsets (u16 units), loop-invariant
  int aoff[4][2], boff[2][2];
#pragma unroll
  for (int m = 0; m < 4; ++m)
#pragma unroll
    for (int ks = 0; ks < 2; ++ks) {
      int row = (wm << 6) + (m << 4) + fr;
      int kb = (ks << 6) + fq;
      aoff[m][ks] = (row << 6) + ((kb ^ ((fr & 7) << 4)) >> 1);
    }
#pragma unroll
  for (int n = 0; n < 2; ++n)
#pragma unroll
    for (int ks = 0; ks < 2; ++ks) {
      int row = (wn << 5) + (n << 4) + fr;
      int kb = (ks << 6) + fq;
      boff[n][ks] = (row << 6) + ((kb ^ ((fr & 7) << 4)) >> 1);
    }
  // stage context: linear LDS dest, inverse-swizzled global source
  StageCtx sc;
#pragma unroll
  for (int s = 0; s < 2; ++s) {
    int c = (s << 9) + tid, row = c >> 3;
    int kbs = (((c & 7) << 4) ^ ((row & 7) << 4));
    sc.go[s] = (size_t)row * K + (kbs >> 1);
    sc.lo[s] = ((s << 9) + (tid & ~63)) << 3;
  }
  const u16* gA0 = A + (size_t)bm * K;
  const u16* gA1 = gA0 + (size_t)128 * K;
  const u16* gB0 = BT + (size_t)bn * K;
  const u16* gB1 = gB0 + (size_t)128 * K;
  f32x4 acc[8][4];
#pragma unroll
  for (int i = 0; i < 8; ++i)
#pragma unroll
    for (int j = 0; j < 4; ++j) acc[i][j] = (f32x4){0.f, 0.f, 0.f, 0.f};
  short8 a0[4][2], a1[4][2], b0[2][2], b1[2][2];
  // prologue: tile 0 all 4 halves, then A0/B0/B1 of tile 1 (A1(1) staged at phi0 of u=0)
  stage_half(gA0, sc, lds + 0);
  stage_half(gA1, sc, lds + 16384);
  stage_half(gB0, sc, lds + 32768);
  stage_half(gB1, sc, lds + 49152);
  stage_half(gA0 + 64, sc, lds + 8192);
  stage_half(gB0 + 64, sc, lds + 32768 + 8192);
  stage_half(gB1 + 64, sc, lds + 49152 + 8192);
  asm volatile("s_waitcnt vmcnt(6)" ::: "memory");   // tile-0's 8 loads landed (own wave)
  __builtin_amdgcn_s_barrier();                      // cross-wave landing
  rdA(lds + 0, aoff, a0);                            // RA0(0)
  rdB(lds + 32768, boff, b0);                        // RB0(0)
  for (int u = 0; u + 2 < NT; ++u)
    ktile<0>(lds, u, gA0, gA1, gB0, gB1, sc, aoff, boff, a0, a1, b0, b1, acc);
  ktile<1>(lds, NT - 2, gA0, gA1, gB0, gB1, sc, aoff, boff, a0, a1, b0, b1, acc);
  ktile<2>(lds, NT - 1, gA0, gA1, gB0, gB1, sc, aoff, boff, a0, a1, b0, b1, acc);
  // epilogue: C/D map col=lane&15 (B side), row=(lane>>4)*4+r (A side)
  const int er = (lane >> 4) << 2, ec = lane & 15;
#pragma unroll
  for (int ai = 0; ai < 8; ++ai) {
    long row0 = bm + ((long)(ai >> 2) << 7) + (wm << 6) + ((ai & 3) << 4) + er;
#pragma unroll
    for (int bj = 0; bj < 4; ++bj) {
      long col = bn + ((long)(bj >> 1) << 7) + (wn << 5) + ((bj & 1) << 4) + ec;
#pragma unroll
      for (int r = 0; r < 4; ++r)
        Cb[(size_t)(row0 + r) * N + col] = f2b(acc[ai][bj][r]);
    }
  }
}

// ---------------- bf16 MFMA GEMM 64x64 tile (max block count for small GEMMs) ----------------
__global__ __launch_bounds__(256, 4)
void k_gemm_wo(const u16* __restrict__ A, const u16* __restrict__ BT,
               float* __restrict__ Cf, int M, int N, int K) {
  __shared__ __align__(16) u16 As[2048];
  __shared__ __align__(16) u16 Bs[2048];
  const int tid = threadIdx.x, wave = tid >> 6, lane = tid & 63;
  const long bm = (long)blockIdx.y << 6, bn = (long)blockIdx.x << 6;
  const int r0 = (wave << 4) + (lane >> 2);
  const int kof = (((lane & 3) ^ ((lane >> 3) & 3)) << 3);
  const u16* gA = A + (bm + r0) * (long)K + kof;
  const u16* gB = BT + (bn + r0) * (long)K + kof;
  u16* lA = As + (wave << 9);
  u16* lB = Bs + (wave << 9);
  const int wr = (wave >> 1) << 5, wc = (wave & 1) << 5;
  const int fr = lane & 15, fq = (lane >> 4) << 3;
  const int fqs = fq ^ (((fr >> 1) & 3) << 3);
  f32x4 acc[2][2];
#pragma unroll
  for (int i = 0; i < 2; ++i)
#pragma unroll
    for (int j = 0; j < 2; ++j) acc[i][j] = (f32x4){0.f, 0.f, 0.f, 0.f};
  for (int k0 = 0; k0 < K; k0 += 32) {
    gl2lds16(gA + k0, lA);
    gl2lds16(gB + k0, lB);
    __syncthreads();
    short8 af[2], bfr[2];
#pragma unroll
    for (int t = 0; t < 2; ++t) {
      af[t]  = *(const short8*)&As[(wr + (t << 4) + fr) * 32 + fqs];
      bfr[t] = *(const short8*)&Bs[(wc + (t << 4) + fr) * 32 + fqs];
    }
#pragma unroll
    for (int i = 0; i < 2; ++i)
#pragma unroll
      for (int j = 0; j < 2; ++j)
        acc[i][j] = mfma_bf16(af[i], bfr[j], acc[i][j]);
    __syncthreads();
  }
  const int er = (lane >> 4) << 2, ec = lane & 15;
#pragma unroll
  for (int i = 0; i < 2; ++i)
#pragma unroll
    for (int j = 0; j < 2; ++j)
#pragma unroll
      for (int r = 0; r < 4; ++r) {
        long row = bm + wr + (i << 4) + er + r;
        long col = bn + wc + (j << 4) + ec;
        Cf[row * N + col] = acc[i][j][r];
      }
}

// ---------------- causal conv(K=4)+SiLU+l2norm (1536 blocks) + beta (128 blocks) ----------------
// beta scratch: 4 waves x 256 floats = 4 KiB. MUST be >= 4096 B (round-6 bug: passed the
// 2 KiB wf array -> overflow corrupted beta). Beta blocks never touch xs (18 KiB), so xs
// serves as the scratch.
DEVI void beta_body(const u16* __restrict__ Xb, const u16* __restrict__ WbT,
                    float* __restrict__ beta, int bb, float* part) {
  int tid = threadIdx.x, w = tid >> 6, lane = tid & 63;
  int t0 = bb << 4;
  int fr = lane & 15, fq = (lane >> 4) << 3;
  const u16* ap = Xb + (size_t)(t0 + fr) * 2048 + (w << 9) + fq;
  const u16* bp = WbT + (size_t)fr * 2048 + (w << 9) + fq;
  f32x4 acc = {0.f, 0.f, 0.f, 0.f};
#pragma unroll
  for (int ks = 0; ks < 16; ++ks)
    acc = mfma_bf16(*(const short8*)(ap + (ks << 5)), *(const short8*)(bp + (ks << 5)), acc);
  int er = (lane >> 4) << 2;
#pragma unroll
  for (int r = 0; r < 4; ++r) part[w * 256 + (er + r) * 16 + fr] = acc[r];
  __syncthreads();
  float s = part[tid] + part[256 + tid] + part[512 + tid] + part[768 + tid];
  beta[(t0 << 4) + tid] = 1.f / (1.f + __expf(-s));
}

__global__ __launch_bounds__(256, 4)
void k_convbeta(const u16* __restrict__ qkv,
                const float* __restrict__ cwq, const float* __restrict__ cwk,
                const float* __restrict__ cwv,
                u16* __restrict__ qn, u16* __restrict__ kn, u16* __restrict__ vn,
                const u16* __restrict__ Xb, const u16* __restrict__ WbT,
                float* __restrict__ beta) {
  __shared__ __align__(16) u16 xs[67 * 136];   // 18224 B; beta blocks reuse as 4KB scratch
  __shared__ float wf[128 * 4];
  int b = blockIdx.x;
  if (b >= 1536) { beta_body(Xb, WbT, beta, b - 1536, (float*)xs); return; }
  int tt = b & 31, s = b >> 5;
  int kind = s >> 4, h = s & 15;
  int t0 = tt << 6;
  int col = (kind << 11) + (h << 7);
  int tid = threadIdx.x;
  const float* cw = (kind == 0) ? cwq : ((kind == 1) ? cwk : cwv);
  if (tid < 128) *(float4*)&wf[tid << 2] = *(const float4*)(cw + (size_t)((h << 7) + tid) * 4);
  // stage rows t0-3 .. t0+63 (67 rows x 128 d), coalesced 16B chunks
  for (int i = tid; i < 1072; i += 256) {
    int prow = i >> 4, c8 = (i & 15) << 3;
    int g = t0 - 3 + prow;
    u16x8 v = {0, 0, 0, 0, 0, 0, 0, 0};
    if (g >= 0) v = *(const u16x8*)(qkv + (size_t)g * 6144 + col + c8);
    *(u16x8*)&xs[prow * 136 + c8] = v;
  }
  __syncthreads();
  int t = tid >> 2, dg = tid & 3;
  float y[32];
  float ss = 0.f;
#pragma unroll
  for (int e8 = 0; e8 < 4; ++e8) {
    int d0 = (dg << 5) + (e8 << 3);
    u16x8 a0 = *(const u16x8*)&xs[(t + 0) * 136 + d0];
    u16x8 a1 = *(const u16x8*)&xs[(t + 1) * 136 + d0];
    u16x8 a2 = *(const u16x8*)&xs[(t + 2) * 136 + d0];
    u16x8 a3 = *(const u16x8*)&xs[(t + 3) * 136 + d0];
#pragma unroll
    for (int e = 0; e < 8; ++e) {
      float4 w = *(const float4*)&wf[(d0 + e) << 2];
      float v = b2f(a0[e]) * w.x + b2f(a1[e]) * w.y + b2f(a2[e]) * w.z + b2f(a3[e]) * w.w;
      v = v / (1.f + __expf(-v));   // SiLU
      y[(e8 << 3) + e] = v;
      ss += v * v;
    }
  }
  float sc = 1.f;
  if (kind < 2) {
    ss += __shfl_xor(ss, 1);
    ss += __shfl_xor(ss, 2);
    sc = rsqrtf(ss + 1e-6f);
    if (kind == 0) sc *= 0.08838834764831843f;  // 128^-0.5
  }
  u16* dst = (kind == 0) ? qn : ((kind == 1) ? kn : vn);
  u16* dp = dst + ((size_t)h << 18) + ((size_t)(t0 + t) << 7) + (dg << 5);
#pragma unroll
  for (int e8 = 0; e8 < 4; ++e8) {
    u16x8 p;
#pragma unroll
    for (int e = 0; e < 8; ++e) p[e] = f2b(y[(e8 << 3) + e] * sc);
    *(u16x8*)(dp + (e8 << 3)) = p;
  }
}

// ---------------- per-(chunk,head) parallel prep (v3) ----------------
__global__ __launch_bounds__(256, 2)
void k_prep(const u16* __restrict__ qn, const u16* __restrict__ kn, const u16* __restrict__ vn,
            const float* __restrict__ beta,
            u16* __restrict__ Gg, u16* __restrict__ Wg,
            u16* __restrict__ KTg, u16* __restrict__ UTg) {
  __shared__ __align__(16) char sm[70912];
  u16*  Kc  = (u16*)sm;                 // 64*136*2 = 17408
  u16*  Qc  = (u16*)(sm + 17408);       // 17408 ; overlay: WR
  u16*  Vc  = (u16*)(sm + 34816);       // 17408
  u16*  KTl = (u16*)(sm + 52224);       // 128*72*2 = 18432 ; overlay: AL (64*64*4)
  float* AL = (float*)(sm + 52224);
  float* Bl = (float*)(sm + 70656);     // 256
  u16*  WR  = Qc;
  int h = blockIdx.x, c = blockIdx.y;
  int tid = threadIdx.x, wave = tid >> 6, lane = tid & 63;
  size_t ch = (size_t)(c * 16 + h);
  const u16* kb = kn + ((size_t)h << 18) + ((size_t)c << 13);
  const u16* qb = qn + ((size_t)h << 18) + ((size_t)c << 13);
  const u16* vb = vn + ((size_t)h << 18) + ((size_t)c << 13);
#pragma unroll
  for (int s = 0; s < 4; ++s) {
    int e = (tid + (s << 8)) << 3;
    int t = e >> 7, d = e & 127;
    *(u16x8*)&Kc[t * 136 + d] = *(const u16x8*)(kb + e);
    *(u16x8*)&Qc[t * 136 + d] = *(const u16x8*)(qb + e);
    *(u16x8*)&Vc[t * 136 + d] = *(const u16x8*)(vb + e);
  }
  if (tid < 64) Bl[tid] = beta[((c << 6) + tid) * 16 + h];
  __syncthreads();
  int fr = lane & 15, fq = (lane >> 4) << 3, q4 = (lane >> 4) << 2;
  int arow = (wave << 4) + fr;
  f32x4 kk[4], qk[4];
#pragma unroll
  for (int ct = 0; ct < 4; ++ct) { kk[ct] = (f32x4){0.f,0.f,0.f,0.f}; qk[ct] = (f32x4){0.f,0.f,0.f,0.f}; }
#pragma unroll
  for (int ks = 0; ks < 4; ++ks) {
    short8 aK = *(const short8*)&Kc[arow * 136 + (ks << 5) + fq];
    short8 aQ = *(const short8*)&Qc[arow * 136 + (ks << 5) + fq];
#pragma unroll
    for (int ct = 0; ct < 4; ++ct) {
      short8 bK = *(const short8*)&Kc[((ct << 4) + fr) * 136 + (ks << 5) + fq];
      kk[ct] = mfma_bf16(aK, bK, kk[ct]);
      qk[ct] = mfma_bf16(aQ, bK, qk[ct]);
    }
  }
#pragma unroll
  for (int ct = 0; ct < 4; ++ct)
#pragma unroll
    for (int r = 0; r < 4; ++r) {
      int i = (wave << 4) + q4 + r, j = (ct << 4) + fr;
      Gg[(ch << 12) + i * 64 + j] = f2b((j <= i) ? qk[ct][r] : 0.f);
    }
  // K^T into KTl
  {
    int d = tid & 127, tg = tid >> 7;
#pragma unroll
    for (int it = 0; it < 4; ++it) {
      int t0 = (tg + (it << 1)) << 3;
      u16x8 pk;
#pragma unroll
      for (int j = 0; j < 8; ++j) pk[j] = Kc[(t0 + j) * 136 + d];
      *(u16x8*)&KTl[d * 72 + t0] = pk;
    }
  }
  __syncthreads();
#pragma unroll
  for (int it = 0; it < 4; ++it) {
    int idx = tid + (it << 8);
    int row = idx >> 3, j8 = (idx & 7) << 3;
    *(u16x8*)(KTg + (ch << 13) + (row << 6) + j8) = *(const u16x8*)&KTl[row * 72 + j8];
  }
  __syncthreads();
  {
    float bi[4];
#pragma unroll
    for (int r = 0; r < 4; ++r) bi[r] = Bl[(wave << 4) + q4 + r];
#pragma unroll
    for (int ct = 0; ct < 4; ++ct)
#pragma unroll
      for (int r = 0; r < 4; ++r) {
        int i = (wave << 4) + q4 + r, j = (ct << 4) + fr;
        AL[i * 64 + j] = (j < i) ? bi[r] * kk[ct][r] : 0.f;
      }
  }
  __syncthreads();
  float X[64];
  {
    const u16* colp = (tid < 128) ? (Kc + tid) : (Vc + (tid - 128));
#pragma unroll
    for (int t = 0; t < 64; ++t) X[t] = Bl[t] * b2f(colp[t * 136]);
#pragma unroll
    for (int r = 1; r < 64; ++r) {
      float s = 0.f;
      const float* Ar = &AL[r * 64];
      int r4 = r & ~3;
#pragma unroll
      for (int l = 0; l < 64; l += 4)
        if (l + 4 <= r) {
          float4 a = *(const float4*)(Ar + l);
          s += a.x * X[l] + a.y * X[l + 1] + a.z * X[l + 2] + a.w * X[l + 3];
        }
#pragma unroll
      for (int l = 0; l < 4; ++l)
        if (r4 + l < r) s += Ar[r4 + l] * X[r4 + l];
      X[r] -= s;
    }
  }
  __syncthreads();   // Qc dead -> WR overlay
  if (tid < 128) {
#pragma unroll
    for (int t = 0; t < 64; ++t) WR[t * 136 + tid] = f2b(X[t]);
  } else {
    int v = tid - 128;
    u16* dstr = UTg + (ch << 13) + (v << 6);
#pragma unroll
    for (int j = 0; j < 8; ++j) {
      u16x8 p;
#pragma unroll
      for (int e = 0; e < 8; ++e) p[e] = f2b(X[(j << 3) + e]);
      *(u16x8*)(dstr + (j << 3)) = p;
    }
  }
  __syncthreads();
#pragma unroll
  for (int it = 0; it < 4; ++it) {
    int idx = tid + (it << 8);
    int row = idx >> 4, j8 = (idx & 15) << 3;
    *(u16x8*)(Wg + (ch << 13) + (row << 7) + j8) = *(const u16x8*)&WR[row * 136 + j8];
  }
}

// ---------------- sequential chunked delta-rule scan (lean) ----------------
struct Frags { short8 q[4], w[4], g[2], k[4]; u16x4 u; };

DEVI void load_frags(Frags& f, const u16* qh, const u16* Wg, const u16* Gg,
                     const u16* KTg, const u16* UTg, int c, int h,
                     int trow, int fr, int fq, int q4, int w, int vbase) {
  const u16* qb = qh + ((size_t)((c << 6) + trow + fr) << 7) + fq;
#pragma unroll
  for (int ks = 0; ks < 4; ++ks) f.q[ks] = *(const short8*)(qb + (ks << 5));
  size_t ch = (size_t)(c * 16 + h);
  const u16* wb = Wg + (ch << 13) + ((size_t)(trow + fr) << 7) + fq;
#pragma unroll
  for (int ks = 0; ks < 4; ++ks) f.w[ks] = *(const short8*)(wb + (ks << 5));
  const u16* gb = Gg + (ch << 12) + ((size_t)(trow + fr) << 6) + fq;
#pragma unroll
  for (int ks = 0; ks < 2; ++ks) f.g[ks] = *(const short8*)(gb + (ks << 5));
  const u16* kbp = KTg + (ch << 13) + ((size_t)(w << 5) << 6) + fq;
#pragma unroll
  for (int dt = 0; dt < 2; ++dt)
#pragma unroll
    for (int ks = 0; ks < 2; ++ks)
      f.k[(dt << 1) | ks] = *(const short8*)(kbp + ((size_t)((dt << 4) + fr) << 6) + (ks << 5));
  f.u = *(const u16x4*)(UTg + (ch << 13) + ((size_t)(vbase + fr) << 6) + trow + q4);
}

DEVI void chunk_body(int c, Frags& f, u16* ST, u16* DT, u16* oh,
                     int trow, int fr, int fq, int q4, int w, int vbase,
                     f32x4& S0, f32x4& S1) {
#pragma unroll
  for (int r = 0; r < 4; ++r) {
    ST[(q4 + r) * 136 + (w << 5) + fr] = f2b(S0[r]);
    ST[(q4 + r) * 136 + (w << 5) + 16 + fr] = f2b(S1[r]);
  }
  barrier_lds();
  short8 sf[4];
#pragma unroll
  for (int ks = 0; ks < 4; ++ks) sf[ks] = *(const short8*)&ST[fr * 136 + (ks << 5) + fq];
  f32x4 racc = {0.f,0.f,0.f,0.f}, oacc = {0.f,0.f,0.f,0.f};
#pragma unroll
  for (int ks = 0; ks < 4; ++ks) {
    racc = mfma_bf16(f.w[ks], sf[ks], racc);
    oacc = mfma_bf16(f.q[ks], sf[ks], oacc);
  }
#pragma unroll
  for (int r = 0; r < 4; ++r)
    DT[fr * 72 + trow + q4 + r] = f2b(b2f(f.u[r]) - racc[r]);
  barrier_lds();
  short8 df[2];
#pragma unroll
  for (int ks = 0; ks < 2; ++ks) df[ks] = *(const short8*)&DT[fr * 72 + (ks << 5) + fq];
#pragma unroll
  for (int ks = 0; ks < 2; ++ks) {
    oacc = mfma_bf16(f.g[ks], df[ks], oacc);
    S0 = mfma_bf16(df[ks], f.k[ks], S0);
    S1 = mfma_bf16(df[ks], f.k[2 | ks], S1);
  }
#pragma unroll
  for (int r = 0; r < 4; ++r)
    oh[(size_t)((c << 6) + trow + q4 + r) * 128 + vbase + fr] = f2b(oacc[r]);
}

__global__ __launch_bounds__(256, 1)
void k_delta(const u16* __restrict__ qn, const u16* __restrict__ Wg,
             const u16* __restrict__ Gg, const u16* __restrict__ KTg,
             const u16* __restrict__ UTg, u16* __restrict__ o) {
  __shared__ __align__(16) u16 ST[16 * 136];
  __shared__ __align__(16) u16 DT[16 * 72];
  int bx = blockIdx.x;
  int h = bx & 15, vbase = (bx >> 4) << 4;
  int tid = threadIdx.x, w = tid >> 6, lane = tid & 63;
  int fr = lane & 15, fq = (lane >> 4) << 3, q4 = (lane >> 4) << 2;
  int trow = w << 4;
  const u16* qh = qn + ((size_t)h << 18);
  u16* oh = o + ((size_t)h << 18);
  f32x4 S0 = {0.f,0.f,0.f,0.f}, S1 = {0.f,0.f,0.f,0.f};
  Frags fa, fb;
  load_frags(fa, qh, Wg, Gg, KTg, UTg, 0, h, trow, fr, fq, q4, w, vbase);
  for (int c = 0; c < 32; c += 2) {
    int c1 = c + 1, c2 = (c + 2 < 32) ? c + 2 : 31;
    load_frags(fb, qh, Wg, Gg, KTg, UTg, c1, h, trow, fr, fq, q4, w, vbase);
    chunk_body(c, fa, ST, DT, oh, trow, fr, fq, q4, w, vbase, S0, S1);
    load_frags(fa, qh, Wg, Gg, KTg, UTg, c2, h, trow, fr, fq, q4, w, vbase);
    chunk_body(c1, fb, ST, DT, oh, trow, fr, fq, q4, w, vbase, S0, S1);
  }
}

// ---------------- per-head RMSNorm on o (bf16), tile version ----------------
// grid (32, 16): 64-token tile x head. thread = (token, 32-d group).
__global__ __launch_bounds__(256, 4)
void k_onorm(const u16* __restrict__ o, const float* __restrict__ onw,
             u16* __restrict__ onb) {
  __shared__ float wl[128];
  int tt = blockIdx.x, h = blockIdx.y, tid = threadIdx.x;
  if (tid < 128) wl[tid] = onw[tid];
  __syncthreads();
  int t = tid >> 2, dg = tid & 3;
  const u16* src = o + ((size_t)h << 18) + ((size_t)((tt << 6) + t) << 7) + (dg << 5);
  u16x8 a[4];
  float ss = 0.f;
#pragma unroll
  for (int e8 = 0; e8 < 4; ++e8) {
    a[e8] = *(const u16x8*)(src + (e8 << 3));
#pragma unroll
    for (int e = 0; e < 8; ++e) { float x = b2f(a[e8][e]); ss += x * x; }
  }
  ss += __shfl_xor(ss, 1);
  ss += __shfl_xor(ss, 2);
  float inv = rsqrtf(ss * (1.f / 128.f) + 1e-6f);
  u16* dp = onb + ((size_t)((tt << 6) + t) << 11) + (h << 7) + (dg << 5);
#pragma unroll
  for (int e8 = 0; e8 < 4; ++e8) {
    u16x8 p;
#pragma unroll
    for (int e = 0; e < 8; ++e)
      p[e] = f2b(b2f(a[e8][e]) * inv * wl[(dg << 5) + (e8 << 3) + e]);
    *(u16x8*)(dp + (e8 << 3)) = p;
  }
}

extern "C" void kernel_launch(void* const* d_in, const int* in_sizes, int n_in,
                              void* d_out, int out_size, void* d_ws, size_t ws_size,
                              hipStream_t stream) {
  (void)in_sizes; (void)n_in; (void)out_size; (void)ws_size;
  const float* hs  = (const float*)d_in[0];
  const float* Wq  = (const float*)d_in[1];
  const float* Wk  = (const float*)d_in[2];
  const float* Wv  = (const float*)d_in[3];
  const float* Wb  = (const float*)d_in[4];
  const float* cwq = (const float*)d_in[5];
  const float* cwk = (const float*)d_in[6];
  const float* cwv = (const float*)d_in[7];
  const float* onw = (const float*)d_in[8];
  const float* Wo  = (const float*)d_in[9];
  float* out = (float*)d_out;
  char* ws = (char*)d_ws;
  const size_t MB = 1ull << 20;
  u16*  Xb   = (u16*)(ws);              //  8 MB  hs bf16 [2048][2048]
  u16*  WT   = (u16*)(ws + 8  * MB);    // 24 MB  [Wq|Wk|Wv]^T bf16 [6144][2048]
  u16*  WoT  = (u16*)(ws + 32 * MB);    //  8 MB  Wo^T bf16
  u16*  QKV  = (u16*)(ws + 40 * MB);    // 24 MB  qkv pre-activations (dead after k_convbeta)
  u16*  Wg   = (u16*)(ws + 40 * MB);    //  8 MB  overlays dead QKV
  u16*  KTg  = (u16*)(ws + 48 * MB);    //  8 MB
  u16*  UTg  = (u16*)(ws + 56 * MB);    //  8 MB
  u16*  qn_  = (u16*)(ws + 64 * MB);    //  8 MB  [16][2048][128]
  u16*  kn_  = (u16*)(ws + 72 * MB);    //  8 MB
  u16*  vn_  = (u16*)(ws + 80 * MB);    //  8 MB
  float* beta= (float*)(ws + 88 * MB);  //  128KB [2048][16]
  u16*  WbT  = (u16*)(ws + 88 * MB + 512 * 1024);  // 64KB [16][2048]
  u16*  Gm   = (u16*)(ws + 89 * MB);    //  4 MB  [32*16][64][64]
  u16*  o_   = (u16*)(ws + 93 * MB);    //  8 MB  bf16 [16][2048][128]
  u16*  onb  = (u16*)(ws + 109 * MB);   //  8 MB  [2048][2048]

  k_pre<<<8320, 256, 0, stream>>>(hs, Xb, Wb, WbT, Wq, Wk, Wv, Wo, WT, WoT);
  k_gemm8p<<<dim3(24, 8), 512, 0, stream>>>(Xb, WT, QKV, 6144, 2048);
  k_convbeta<<<1664, 256, 0, stream>>>(QKV, cwq, cwk, cwv, qn_, kn_, vn_, Xb, WbT, beta);
  k_prep<<<dim3(16, 32), 256, 0, stream>>>(qn_, kn_, vn_, beta, Gm, Wg, KTg, UTg);
  k_delta<<<128, 256, 0, stream>>>(qn_, Wg, Gm, KTg, UTg, o_);
  k_onorm<<<dim3(32, 16), 256, 0, stream>>>(o_, onw, onb);
  k_gemm_wo<<<dim3(32, 32), 256, 0, stream>>>(onb, WoT, out, 2048, 2048, 2048);
}

// Round 8
// 326.995 us; speedup vs baseline: 1.0651x; 1.0155x over previous
//
#include <hip/hip_runtime.h>

typedef unsigned short u16;
typedef __attribute__((ext_vector_type(4))) unsigned short u16x4;
typedef __attribute__((ext_vector_type(8))) unsigned short u16x8;
typedef __attribute__((ext_vector_type(8))) short short8;
typedef __attribute__((ext_vector_type(4))) float f32x4;

#define DEVI __device__ __forceinline__

DEVI u16 f2b(float f) {
  union { float f; unsigned u; } x; x.f = f;
  unsigned r = (x.u + 0x7fffu + ((x.u >> 16) & 1u)) >> 16;
  return (u16)r;
}
DEVI float b2f(u16 h) {
  union { unsigned u; float f; } x; x.u = ((unsigned)h) << 16;
  return x.f;
}
DEVI f32x4 mfma_bf16(short8 a, short8 b, f32x4 c) {
  return __builtin_amdgcn_mfma_f32_16x16x32_bf16(a, b, c, 0, 0, 0);
}
DEVI void gl2lds16(const u16* g, u16* l) {
  __builtin_amdgcn_global_load_lds((__attribute__((address_space(1))) void*)g,
                                   (__attribute__((address_space(3))) void*)l,
                                   16, 0, 0);
}
// barrier that drains only LDS (lgkmcnt), NOT vmcnt -> global prefetch stays in flight
DEVI void barrier_lds() {
  asm volatile("s_waitcnt lgkmcnt(0)\n\ts_barrier" ::: "memory");
}

// ---- fused input prep: fp32->bf16 cvt (hs) + WbT build + 4x 64x64-tile transpose ----
// blocks [0,4096): hs cvt; [4096,4224): WbT; [4224,8320): transposes of Wq/Wk/Wv/Wo.
__global__ __launch_bounds__(256)
void k_pre(const float* __restrict__ hs, u16* __restrict__ Xb,
           const float* __restrict__ Wb, u16* __restrict__ WbT,
           const float* __restrict__ Wq, const float* __restrict__ Wk,
           const float* __restrict__ Wv, const float* __restrict__ Wo,
           u16* __restrict__ WT, u16* __restrict__ WoT) {
  __shared__ u16 tile[64 * 66];
  int b = blockIdx.x;
  if (b < 4096) {
    int i = b * 256 + threadIdx.x;
    float4 v = ((const float4*)hs)[i];
    u16x4 r; r.x = f2b(v.x); r.y = f2b(v.y); r.z = f2b(v.z); r.w = f2b(v.w);
    ((u16x4*)Xb)[i] = r;
    return;
  }
  if (b < 4224) {
    int j = (b - 4096) * 256 + threadIdx.x;   // 0..32767
    int n = j >> 11, k = j & 2047;
    WbT[j] = f2b(Wb[k * 16 + n]);
    return;
  }
  const int RC = 2048;
  int tb = b - 4224;                  // 0..4095
  int z = tb >> 10, t = tb & 1023;
  const float* src = (z == 0) ? Wq : (z == 1) ? Wk : (z == 2) ? Wv : Wo;
  u16* dst = (z == 0) ? WT : (z == 1) ? (WT + 2048 * 2048)
           : (z == 2) ? (WT + 2 * 2048 * 2048) : WoT;
  int bx = (t & 31) << 6, by = (t >> 5) << 6;
  int x = threadIdx.x & 63, g = threadIdx.x >> 6;
#pragma unroll
  for (int i = 0; i < 16; ++i) {
    int r = (i << 2) + g;
    tile[x * 66 + r] = f2b(src[(size_t)(by + r) * RC + bx + x]);  // transposed into LDS
  }
  __syncthreads();
#pragma unroll
  for (int i = 0; i < 16; ++i) {
    int r = (i << 2) + g;
    dst[(size_t)(bx + r) * RC + by + x] = tile[r * 66 + x];       // 128B coalesced rows
  }
}

// ============ 8-phase 256x256 bf16 MFMA GEMM, ds_reads pipelined one phase ahead ============
// (round-2 schedule — measured best at 59.9us. 1 barrier/phase, reads issued one phase
//  before use, compiler emits counted lgkmcnt. sched_barrier pinning tested: neutral;
//  m201-style 2-barrier + lgkmcnt(0): regression. Do not re-add without new evidence.)
// C[M][N] = A[M][K] @ BT[N][K]^T. BM=BN=256, BK=64, 512 thr = 8 waves (2x4).
// LDS 128 KiB = {A0,A1,B0,B1} x {slot0,slot1} x (128 rows x 64 k) bf16.
// vmcnt(4) at phi2-end proves all four halves of tile u+1 landed before phi3 issues
// next-tile reads. Stage order: phi0->A1(u+1), phi1->A0(u+2), phi2->B0(u+2), phi3->B1(u+2).
// LDS XOR-swizzled reads; inverse swizzle on the per-lane GLOBAL source (rule 21).
// Grid note: (24,8) keeps each B-panel's 8 consumer blocks on ONE XCD (24%8==0) — B
// is already XCD-local; A-localizing swap is worse (200MB vs 88MB L2-fill). No swizzle.

struct StageCtx { size_t go[2]; int lo[2]; };

DEVI void stage_half(const u16* g, const StageCtx& sc, u16* l) {
  gl2lds16(g + sc.go[0], l + sc.lo[0]);
  gl2lds16(g + sc.go[1], l + sc.lo[1]);
}

DEVI void rdA(const u16* h, const int (&aoff)[4][2], short8 (&a)[4][2]) {
#pragma unroll
  for (int m = 0; m < 4; ++m) {
    a[m][0] = *(const short8*)(h + aoff[m][0]);
    a[m][1] = *(const short8*)(h + aoff[m][1]);
  }
}
DEVI void rdB(const u16* h, const int (&boff)[2][2], short8 (&b)[2][2]) {
#pragma unroll
  for (int n = 0; n < 2; ++n) {
    b[n][0] = *(const short8*)(h + boff[n][0]);
    b[n][1] = *(const short8*)(h + boff[n][1]);
  }
}

template <int QA, int QB>
DEVI void mmquad(const short8 (&a)[4][2], const short8 (&b)[2][2], f32x4 (&acc)[8][4]) {
  __builtin_amdgcn_s_setprio(1);
#pragma unroll
  for (int m = 0; m < 4; ++m)
#pragma unroll
    for (int n = 0; n < 2; ++n) {
      acc[(QA << 2) + m][(QB << 1) + n] =
          mfma_bf16(a[m][0], b[n][0], acc[(QA << 2) + m][(QB << 1) + n]);
      acc[(QA << 2) + m][(QB << 1) + n] =
          mfma_bf16(a[m][1], b[n][1], acc[(QA << 2) + m][(QB << 1) + n]);
    }
  __builtin_amdgcn_s_setprio(0);
}

template <int MODE>  // 0 = steady, 1 = u == NT-2, 2 = u == NT-1
DEVI void ktile(u16* lds, int u,
                const u16* gA0, const u16* gA1, const u16* gB0, const u16* gB1,
                const StageCtx& sc,
                const int (&aoff)[4][2], const int (&boff)[2][2],
                short8 (&a0)[4][2], short8 (&a1)[4][2],
                short8 (&b0)[2][2], short8 (&b1)[2][2],
                f32x4 (&acc)[8][4]) {
  const int cs = (u & 1) << 13, ns = ((u + 1) & 1) << 13;
  const u16* A1c = lds + 16384 + cs;
  const u16* B1c = lds + 49152 + cs;
  const size_t uo1 = (size_t)(u + 1) << 6, uo2 = (size_t)(u + 2) << 6;
  // ---- phase 0: MFMA quad(0,0) = a0*b0; issue RB1(u); stage A1(u+1)
  __builtin_amdgcn_s_barrier();
  rdB(B1c, boff, b1);
  if constexpr (MODE <= 1) stage_half(gA1 + uo1, sc, lds + 16384 + ns);
  mmquad<0, 0>(a0, b0, acc);
  // ---- phase 1: MFMA quad(0,1) = a0*b1; issue RA1(u); stage A0(u+2)
  __builtin_amdgcn_s_barrier();
  rdA(A1c, aoff, a1);
  if constexpr (MODE == 0) stage_half(gA0 + uo2, sc, lds + cs);
  mmquad<0, 1>(a0, b1, acc);
  // ---- phase 2: MFMA quad(1,0) = a1*b0; stage B0(u+2); counted vmcnt
  __builtin_amdgcn_s_barrier();
  if constexpr (MODE == 0) stage_half(gB0 + uo2, sc, lds + 32768 + cs);
  mmquad<1, 0>(a1, b0, acc);
  if constexpr (MODE == 0) asm volatile("s_waitcnt vmcnt(4)" ::: "memory");
  if constexpr (MODE == 1) asm volatile("s_waitcnt vmcnt(0)" ::: "memory");
  // ---- phase 3: MFMA quad(1,1) = a1*b1; issue next-tile RA0/RB0; stage B1(u+2)
  __builtin_amdgcn_s_barrier();
  if constexpr (MODE <= 1) {
    rdA(lds + ns, aoff, a0);
    rdB(lds + 32768 + ns, boff, b0);
  }
  if constexpr (MODE == 0) stage_half(gB1 + uo2, sc, lds + 49152 + cs);
  mmquad<1, 1>(a1, b1, acc);
}

__global__ __launch_bounds__(512, 2)
void k_gemm8p(const u16* __restrict__ A, const u16* __restrict__ BT,
              u16* __restrict__ Cb, int N, int K) {
  __shared__ __align__(16) u16 lds[65536];   // 128 KiB
  const int tid = threadIdx.x, wave = tid >> 6, lane = tid & 63;
  const int wm = wave >> 2, wn = wave & 3;
  const int fr = lane & 15, fq = (lane >> 4) << 4;   // fq in BYTES
  const long bm = (long)blockIdx.y << 8, bn = (long)blockIdx.x << 8;
  const int NT = K >> 6;
  // precomputed swizzled LDS read offsets (u16 units), loop-invariant
  int aoff[4][2], boff[2][2];
#pragma unroll
  for (int m = 0; m < 4; ++m)
#pragma unroll
    for (int ks = 0; ks < 2; ++ks) {
      int row = (wm << 6) + (m << 4) + fr;
      int kb = (ks << 6) + fq;
      aoff[m][ks] = (row << 6) + ((kb ^ ((fr & 7) << 4)) >> 1);
    }
#pragma unroll
  for (int n = 0; n < 2; ++n)
#pragma unroll
    for (int ks = 0; ks < 2; ++ks) {
      int row = (wn << 5) + (n << 4) + fr;
      int kb = (ks << 6) + fq;
      boff[n][ks] = (row << 6) + ((kb ^ ((fr & 7) << 4)) >> 1);
    }
  // stage context: linear LDS dest, inverse-swizzled global source
  StageCtx sc;
#pragma unroll
  for (int s = 0; s < 2; ++s) {
    int c = (s << 9) + tid, row = c >> 3;
    int kbs = (((c & 7) << 4) ^ ((row & 7) << 4));
    sc.go[s] = (size_t)row * K + (kbs >> 1);
    sc.lo[s] = ((s << 9) + (tid & ~63)) << 3;
  }
  const u16* gA0 = A + (size_t)bm * K;
  const u16* gA1 = gA0 + (size_t)128 * K;
  const u16* gB0 = BT + (size_t)bn * K;
  const u16* gB1 = gB0 + (size_t)128 * K;
  f32x4 acc[8][4];
#pragma unroll
  for (int i = 0; i < 8; ++i)
#pragma unroll
    for (int j = 0; j < 4; ++j) acc[i][j] = (f32x4){0.f, 0.f, 0.f, 0.f};
  short8 a0[4][2], a1[4][2], b0[2][2], b1[2][2];
  // prologue: tile 0 all 4 halves, then A0/B0/B1 of tile 1 (A1(1) staged at phi0 of u=0)
  stage_half(gA0, sc, lds + 0);
  stage_half(gA1, sc, lds + 16384);
  stage_half(gB0, sc, lds + 32768);
  stage_half(gB1, sc, lds + 49152);
  stage_half(gA0 + 64, sc, lds + 8192);
  stage_half(gB0 + 64, sc, lds + 32768 + 8192);
  stage_half(gB1 + 64, sc, lds + 49152 + 8192);
  asm volatile("s_waitcnt vmcnt(6)" ::: "memory");   // tile-0's 8 loads landed (own wave)
  __builtin_amdgcn_s_barrier();                      // cross-wave landing
  rdA(lds + 0, aoff, a0);                            // RA0(0)
  rdB(lds + 32768, boff, b0);                        // RB0(0)
  for (int u = 0; u + 2 < NT; ++u)
    ktile<0>(lds, u, gA0, gA1, gB0, gB1, sc, aoff, boff, a0, a1, b0, b1, acc);
  ktile<1>(lds, NT - 2, gA0, gA1, gB0, gB1, sc, aoff, boff, a0, a1, b0, b1, acc);
  ktile<2>(lds, NT - 1, gA0, gA1, gB0, gB1, sc, aoff, boff, a0, a1, b0, b1, acc);
  // epilogue: C/D map col=lane&15 (B side), row=(lane>>4)*4+r (A side)
  const int er = (lane >> 4) << 2, ec = lane & 15;
#pragma unroll
  for (int ai = 0; ai < 8; ++ai) {
    long row0 = bm + ((long)(ai >> 2) << 7) + (wm << 6) + ((ai & 3) << 4) + er;
#pragma unroll
    for (int bj = 0; bj < 4; ++bj) {
      long col = bn + ((long)(bj >> 1) << 7) + (wn << 5) + ((bj & 1) << 4) + ec;
#pragma unroll
      for (int r = 0; r < 4; ++r)
        Cb[(size_t)(row0 + r) * N + col] = f2b(acc[ai][bj][r]);
    }
  }
}

// ---------------- bf16 MFMA GEMM 64x64 tile (max block count for small GEMMs) ----------------
__global__ __launch_bounds__(256, 4)
void k_gemm_wo(const u16* __restrict__ A, const u16* __restrict__ BT,
               float* __restrict__ Cf, int M, int N, int K) {
  __shared__ __align__(16) u16 As[2048];
  __shared__ __align__(16) u16 Bs[2048];
  const int tid = threadIdx.x, wave = tid >> 6, lane = tid & 63;
  const long bm = (long)blockIdx.y << 6, bn = (long)blockIdx.x << 6;
  const int r0 = (wave << 4) + (lane >> 2);
  const int kof = (((lane & 3) ^ ((lane >> 3) & 3)) << 3);
  const u16* gA = A + (bm + r0) * (long)K + kof;
  const u16* gB = BT + (bn + r0) * (long)K + kof;
  u16* lA = As + (wave << 9);
  u16* lB = Bs + (wave << 9);
  const int wr = (wave >> 1) << 5, wc = (wave & 1) << 5;
  const int fr = lane & 15, fq = (lane >> 4) << 3;
  const int fqs = fq ^ (((fr >> 1) & 3) << 3);
  f32x4 acc[2][2];
#pragma unroll
  for (int i = 0; i < 2; ++i)
#pragma unroll
    for (int j = 0; j < 2; ++j) acc[i][j] = (f32x4){0.f, 0.f, 0.f, 0.f};
  for (int k0 = 0; k0 < K; k0 += 32) {
    gl2lds16(gA + k0, lA);
    gl2lds16(gB + k0, lB);
    __syncthreads();
    short8 af[2], bfr[2];
#pragma unroll
    for (int t = 0; t < 2; ++t) {
      af[t]  = *(const short8*)&As[(wr + (t << 4) + fr) * 32 + fqs];
      bfr[t] = *(const short8*)&Bs[(wc + (t << 4) + fr) * 32 + fqs];
    }
#pragma unroll
    for (int i = 0; i < 2; ++i)
#pragma unroll
      for (int j = 0; j < 2; ++j)
        acc[i][j] = mfma_bf16(af[i], bfr[j], acc[i][j]);
    __syncthreads();
  }
  const int er = (lane >> 4) << 2, ec = lane & 15;
#pragma unroll
  for (int i = 0; i < 2; ++i)
#pragma unroll
    for (int j = 0; j < 2; ++j)
#pragma unroll
      for (int r = 0; r < 4; ++r) {
        long row = bm + wr + (i << 4) + er + r;
        long col = bn + wc + (j << 4) + ec;
        Cf[row * N + col] = acc[i][j][r];
      }
}

// ---------------- causal conv(K=4)+SiLU+l2norm (1536 blocks) + beta (128 blocks) ----------------
// beta scratch: 4 waves x 256 floats = 4 KiB. MUST be >= 4096 B (round-6 bug: passed the
// 2 KiB wf array -> overflow corrupted beta). Beta blocks never touch xs (18 KiB), so xs
// serves as the scratch.
DEVI void beta_body(const u16* __restrict__ Xb, const u16* __restrict__ WbT,
                    float* __restrict__ beta, int bb, float* part) {
  int tid = threadIdx.x, w = tid >> 6, lane = tid & 63;
  int t0 = bb << 4;
  int fr = lane & 15, fq = (lane >> 4) << 3;
  const u16* ap = Xb + (size_t)(t0 + fr) * 2048 + (w << 9) + fq;
  const u16* bp = WbT + (size_t)fr * 2048 + (w << 9) + fq;
  f32x4 acc = {0.f, 0.f, 0.f, 0.f};
#pragma unroll
  for (int ks = 0; ks < 16; ++ks)
    acc = mfma_bf16(*(const short8*)(ap + (ks << 5)), *(const short8*)(bp + (ks << 5)), acc);
  int er = (lane >> 4) << 2;
#pragma unroll
  for (int r = 0; r < 4; ++r) part[w * 256 + (er + r) * 16 + fr] = acc[r];
  __syncthreads();
  float s = part[tid] + part[256 + tid] + part[512 + tid] + part[768 + tid];
  beta[(t0 << 4) + tid] = 1.f / (1.f + __expf(-s));
}

__global__ __launch_bounds__(256, 4)
void k_convbeta(const u16* __restrict__ qkv,
                const float* __restrict__ cwq, const float* __restrict__ cwk,
                const float* __restrict__ cwv,
                u16* __restrict__ qn, u16* __restrict__ kn, u16* __restrict__ vn,
                const u16* __restrict__ Xb, const u16* __restrict__ WbT,
                float* __restrict__ beta) {
  __shared__ __align__(16) u16 xs[67 * 136];   // 18224 B; beta blocks reuse as 4KB scratch
  __shared__ float wf[128 * 4];
  int b = blockIdx.x;
  if (b >= 1536) { beta_body(Xb, WbT, beta, b - 1536, (float*)xs); return; }
  int tt = b & 31, s = b >> 5;
  int kind = s >> 4, h = s & 15;
  int t0 = tt << 6;
  int col = (kind << 11) + (h << 7);
  int tid = threadIdx.x;
  const float* cw = (kind == 0) ? cwq : ((kind == 1) ? cwk : cwv);
  if (tid < 128) *(float4*)&wf[tid << 2] = *(const float4*)(cw + (size_t)((h << 7) + tid) * 4);
  // stage rows t0-3 .. t0+63 (67 rows x 128 d), coalesced 16B chunks
  for (int i = tid; i < 1072; i += 256) {
    int prow = i >> 4, c8 = (i & 15) << 3;
    int g = t0 - 3 + prow;
    u16x8 v = {0, 0, 0, 0, 0, 0, 0, 0};
    if (g >= 0) v = *(const u16x8*)(qkv + (size_t)g * 6144 + col + c8);
    *(u16x8*)&xs[prow * 136 + c8] = v;
  }
  __syncthreads();
  int t = tid >> 2, dg = tid & 3;
  float y[32];
  float ss = 0.f;
#pragma unroll
  for (int e8 = 0; e8 < 4; ++e8) {
    int d0 = (dg << 5) + (e8 << 3);
    u16x8 a0 = *(const u16x8*)&xs[(t + 0) * 136 + d0];
    u16x8 a1 = *(const u16x8*)&xs[(t + 1) * 136 + d0];
    u16x8 a2 = *(const u16x8*)&xs[(t + 2) * 136 + d0];
    u16x8 a3 = *(const u16x8*)&xs[(t + 3) * 136 + d0];
#pragma unroll
    for (int e = 0; e < 8; ++e) {
      float4 w = *(const float4*)&wf[(d0 + e) << 2];
      float v = b2f(a0[e]) * w.x + b2f(a1[e]) * w.y + b2f(a2[e]) * w.z + b2f(a3[e]) * w.w;
      v = v / (1.f + __expf(-v));   // SiLU
      y[(e8 << 3) + e] = v;
      ss += v * v;
    }
  }
  float sc = 1.f;
  if (kind < 2) {
    ss += __shfl_xor(ss, 1);
    ss += __shfl_xor(ss, 2);
    sc = rsqrtf(ss + 1e-6f);
    if (kind == 0) sc *= 0.08838834764831843f;  // 128^-0.5
  }
  u16* dst = (kind == 0) ? qn : ((kind == 1) ? kn : vn);
  u16* dp = dst + ((size_t)h << 18) + ((size_t)(t0 + t) << 7) + (dg << 5);
#pragma unroll
  for (int e8 = 0; e8 < 4; ++e8) {
    u16x8 p;
#pragma unroll
    for (int e = 0; e < 8; ++e) p[e] = f2b(y[(e8 << 3) + e] * sc);
    *(u16x8*)(dp + (e8 << 3)) = p;
  }
}

// ---------------- per-(chunk,head) parallel prep (v3) ----------------
// Forward substitution X = (I + tril(A))^{-1} b with X in VGPRs. Template recursion
// forces compile-time row indices: the previous #pragma unroll on the 63-iter loop was
// NOT unrolled by the compiler (VGPR_Count=88 < the 96+ X needs), leaving runtime
// indexing -> X[64] in scratch (rule #20) -> every access an L2 round-trip -> 79us
// latency-bound kernel. Two partial sums also break the strict-FP serial add chain.
template <int R>
struct FSub {
  static DEVI void run(float (&X)[64], const float* __restrict__ AL) {
    const float* Ar = AL + R * 64;
    float s0 = 0.f, s1 = 0.f;
#pragma unroll
    for (int l = 0; l + 4 <= R; l += 4) {
      float4 a = *(const float4*)(Ar + l);
      s0 += a.x * X[l];
      s1 += a.y * X[l + 1];
      s0 += a.z * X[l + 2];
      s1 += a.w * X[l + 3];
    }
#pragma unroll
    for (int l = R & ~3; l < R; ++l) s0 += Ar[l] * X[l];
    X[R] -= s0 + s1;
    FSub<R + 1>::run(X, AL);
  }
};
template <>
struct FSub<64> { static DEVI void run(float (&)[64], const float*) {} };

__global__ __launch_bounds__(256, 2)
void k_prep(const u16* __restrict__ qn, const u16* __restrict__ kn, const u16* __restrict__ vn,
            const float* __restrict__ beta,
            u16* __restrict__ Gg, u16* __restrict__ Wg,
            u16* __restrict__ KTg, u16* __restrict__ UTg) {
  __shared__ __align__(16) char sm[70912];
  u16*  Kc  = (u16*)sm;                 // 64*136*2 = 17408
  u16*  Qc  = (u16*)(sm + 17408);       // 17408 ; overlay: WR
  u16*  Vc  = (u16*)(sm + 34816);       // 17408
  u16*  KTl = (u16*)(sm + 52224);       // 128*72*2 = 18432 ; overlay: AL (64*64*4)
  float* AL = (float*)(sm + 52224);
  float* Bl = (float*)(sm + 70656);     // 256
  u16*  WR  = Qc;
  int h = blockIdx.x, c = blockIdx.y;
  int tid = threadIdx.x, wave = tid >> 6, lane = tid & 63;
  size_t ch = (size_t)(c * 16 + h);
  const u16* kb = kn + ((size_t)h << 18) + ((size_t)c << 13);
  const u16* qb = qn + ((size_t)h << 18) + ((size_t)c << 13);
  const u16* vb = vn + ((size_t)h << 18) + ((size_t)c << 13);
#pragma unroll
  for (int s = 0; s < 4; ++s) {
    int e = (tid + (s << 8)) << 3;
    int t = e >> 7, d = e & 127;
    *(u16x8*)&Kc[t * 136 + d] = *(const u16x8*)(kb + e);
    *(u16x8*)&Qc[t * 136 + d] = *(const u16x8*)(qb + e);
    *(u16x8*)&Vc[t * 136 + d] = *(const u16x8*)(vb + e);
  }
  if (tid < 64) Bl[tid] = beta[((c << 6) + tid) * 16 + h];
  __syncthreads();
  int fr = lane & 15, fq = (lane >> 4) << 3, q4 = (lane >> 4) << 2;
  int arow = (wave << 4) + fr;
  f32x4 kk[4], qk[4];
#pragma unroll
  for (int ct = 0; ct < 4; ++ct) { kk[ct] = (f32x4){0.f,0.f,0.f,0.f}; qk[ct] = (f32x4){0.f,0.f,0.f,0.f}; }
#pragma unroll
  for (int ks = 0; ks < 4; ++ks) {
    short8 aK = *(const short8*)&Kc[arow * 136 + (ks << 5) + fq];
    short8 aQ = *(const short8*)&Qc[arow * 136 + (ks << 5) + fq];
#pragma unroll
    for (int ct = 0; ct < 4; ++ct) {
      short8 bK = *(const short8*)&Kc[((ct << 4) + fr) * 136 + (ks << 5) + fq];
      kk[ct] = mfma_bf16(aK, bK, kk[ct]);
      qk[ct] = mfma_bf16(aQ, bK, qk[ct]);
    }
  }
#pragma unroll
  for (int ct = 0; ct < 4; ++ct)
#pragma unroll
    for (int r = 0; r < 4; ++r) {
      int i = (wave << 4) + q4 + r, j = (ct << 4) + fr;
      Gg[(ch << 12) + i * 64 + j] = f2b((j <= i) ? qk[ct][r] : 0.f);
    }
  // K^T into KTl
  {
    int d = tid & 127, tg = tid >> 7;
#pragma unroll
    for (int it = 0; it < 4; ++it) {
      int t0 = (tg + (it << 1)) << 3;
      u16x8 pk;
#pragma unroll
      for (int j = 0; j < 8; ++j) pk[j] = Kc[(t0 + j) * 136 + d];
      *(u16x8*)&KTl[d * 72 + t0] = pk;
    }
  }
  __syncthreads();
#pragma unroll
  for (int it = 0; it < 4; ++it) {
    int idx = tid + (it << 8);
    int row = idx >> 3, j8 = (idx & 7) << 3;
    *(u16x8*)(KTg + (ch << 13) + (row << 6) + j8) = *(const u16x8*)&KTl[row * 72 + j8];
  }
  __syncthreads();
  {
    float bi[4];
#pragma unroll
    for (int r = 0; r < 4; ++r) bi[r] = Bl[(wave << 4) + q4 + r];
#pragma unroll
    for (int ct = 0; ct < 4; ++ct)
#pragma unroll
      for (int r = 0; r < 4; ++r) {
        int i = (wave << 4) + q4 + r, j = (ct << 4) + fr;
        AL[i * 64 + j] = (j < i) ? bi[r] * kk[ct][r] : 0.f;
      }
  }
  __syncthreads();
  float X[64];
  {
    const u16* colp = (tid < 128) ? (Kc + tid) : (Vc + (tid - 128));
#pragma unroll
    for (int t = 0; t < 64; ++t) X[t] = Bl[t] * b2f(colp[t * 136]);
    FSub<1>::run(X, AL);
  }
  __syncthreads();   // Qc dead -> WR overlay
  if (tid < 128) {
#pragma unroll
    for (int t = 0; t < 64; ++t) WR[t * 136 + tid] = f2b(X[t]);
  } else {
    int v = tid - 128;
    u16* dstr = UTg + (ch << 13) + (v << 6);
#pragma unroll
    for (int j = 0; j < 8; ++j) {
      u16x8 p;
#pragma unroll
      for (int e = 0; e < 8; ++e) p[e] = f2b(X[(j << 3) + e]);
      *(u16x8*)(dstr + (j << 3)) = p;
    }
  }
  __syncthreads();
#pragma unroll
  for (int it = 0; it < 4; ++it) {
    int idx = tid + (it << 8);
    int row = idx >> 4, j8 = (idx & 15) << 3;
    *(u16x8*)(Wg + (ch << 13) + (row << 7) + j8) = *(const u16x8*)&WR[row * 136 + j8];
  }
}

// ---------------- sequential chunked delta-rule scan (lean) ----------------
struct Frags { short8 q[4], w[4], g[2], k[4]; u16x4 u; };

DEVI void load_frags(Frags& f, const u16* qh, const u16* Wg, const u16* Gg,
                     const u16* KTg, const u16* UTg, int c, int h,
                     int trow, int fr, int fq, int q4, int w, int vbase) {
  const u16* qb = qh + ((size_t)((c << 6) + trow + fr) << 7) + fq;
#pragma unroll
  for (int ks = 0; ks < 4; ++ks) f.q[ks] = *(const short8*)(qb + (ks << 5));
  size_t ch = (size_t)(c * 16 + h);
  const u16* wb = Wg + (ch << 13) + ((size_t)(trow + fr) << 7) + fq;
#pragma unroll
  for (int ks = 0; ks < 4; ++ks) f.w[ks] = *(const short8*)(wb + (ks << 5));
  const u16* gb = Gg + (ch << 12) + ((size_t)(trow + fr) << 6) + fq;
#pragma unroll
  for (int ks = 0; ks < 2; ++ks) f.g[ks] = *(const short8*)(gb + (ks << 5));
  const u16* kbp = KTg + (ch << 13) + ((size_t)(w << 5) << 6) + fq;
#pragma unroll
  for (int dt = 0; dt < 2; ++dt)
#pragma unroll
    for (int ks = 0; ks < 2; ++ks)
      f.k[(dt << 1) | ks] = *(const short8*)(kbp + ((size_t)((dt << 4) + fr) << 6) + (ks << 5));
  f.u = *(const u16x4*)(UTg + (ch << 13) + ((size_t)(vbase + fr) << 6) + trow + q4);
}

DEVI void chunk_body(int c, Frags& f, u16* ST, u16* DT, u16* oh,
                     int trow, int fr, int fq, int q4, int w, int vbase,
                     f32x4& S0, f32x4& S1) {
#pragma unroll
  for (int r = 0; r < 4; ++r) {
    ST[(q4 + r) * 136 + (w << 5) + fr] = f2b(S0[r]);
    ST[(q4 + r) * 136 + (w << 5) + 16 + fr] = f2b(S1[r]);
  }
  barrier_lds();
  short8 sf[4];
#pragma unroll
  for (int ks = 0; ks < 4; ++ks) sf[ks] = *(const short8*)&ST[fr * 136 + (ks << 5) + fq];
  f32x4 racc = {0.f,0.f,0.f,0.f}, oacc = {0.f,0.f,0.f,0.f};
#pragma unroll
  for (int ks = 0; ks < 4; ++ks) {
    racc = mfma_bf16(f.w[ks], sf[ks], racc);
    oacc = mfma_bf16(f.q[ks], sf[ks], oacc);
  }
#pragma unroll
  for (int r = 0; r < 4; ++r)
    DT[fr * 72 + trow + q4 + r] = f2b(b2f(f.u[r]) - racc[r]);
  barrier_lds();
  short8 df[2];
#pragma unroll
  for (int ks = 0; ks < 2; ++ks) df[ks] = *(const short8*)&DT[fr * 72 + (ks << 5) + fq];
#pragma unroll
  for (int ks = 0; ks < 2; ++ks) {
    oacc = mfma_bf16(f.g[ks], df[ks], oacc);
    S0 = mfma_bf16(df[ks], f.k[ks], S0);
    S1 = mfma_bf16(df[ks], f.k[2 | ks], S1);
  }
#pragma unroll
  for (int r = 0; r < 4; ++r)
    oh[(size_t)((c << 6) + trow + q4 + r) * 128 + vbase + fr] = f2b(oacc[r]);
}

__global__ __launch_bounds__(256, 1)
void k_delta(const u16* __restrict__ qn, const u16* __restrict__ Wg,
             const u16* __restrict__ Gg, const u16* __restrict__ KTg,
             const u16* __restrict__ UTg, u16* __restrict__ o) {
  __shared__ __align__(16) u16 ST[16 * 136];
  __shared__ __align__(16) u16 DT[16 * 72];
  int bx = blockIdx.x;
  int h = bx & 15, vbase = (bx >> 4) << 4;
  int tid = threadIdx.x, w = tid >> 6, lane = tid & 63;
  int fr = lane & 15, fq = (lane >> 4) << 3, q4 = (lane >> 4) << 2;
  int trow = w << 4;
  const u16* qh = qn + ((size_t)h << 18);
  u16* oh = o + ((size_t)h << 18);
  f32x4 S0 = {0.f,0.f,0.f,0.f}, S1 = {0.f,0.f,0.f,0.f};
  Frags fa, fb;
  load_frags(fa, qh, Wg, Gg, KTg, UTg, 0, h, trow, fr, fq, q4, w, vbase);
  for (int c = 0; c < 32; c += 2) {
    int c1 = c + 1, c2 = (c + 2 < 32) ? c + 2 : 31;
    load_frags(fb, qh, Wg, Gg, KTg, UTg, c1, h, trow, fr, fq, q4, w, vbase);
    chunk_body(c, fa, ST, DT, oh, trow, fr, fq, q4, w, vbase, S0, S1);
    load_frags(fa, qh, Wg, Gg, KTg, UTg, c2, h, trow, fr, fq, q4, w, vbase);
    chunk_body(c1, fb, ST, DT, oh, trow, fr, fq, q4, w, vbase, S0, S1);
  }
}

// ---------------- per-head RMSNorm on o (bf16), tile version ----------------
// grid (32, 16): 64-token tile x head. thread = (token, 32-d group).
__global__ __launch_bounds__(256, 4)
void k_onorm(const u16* __restrict__ o, const float* __restrict__ onw,
             u16* __restrict__ onb) {
  __shared__ float wl[128];
  int tt = blockIdx.x, h = blockIdx.y, tid = threadIdx.x;
  if (tid < 128) wl[tid] = onw[tid];
  __syncthreads();
  int t = tid >> 2, dg = tid & 3;
  const u16* src = o + ((size_t)h << 18) + ((size_t)((tt << 6) + t) << 7) + (dg << 5);
  u16x8 a[4];
  float ss = 0.f;
#pragma unroll
  for (int e8 = 0; e8 < 4; ++e8) {
    a[e8] = *(const u16x8*)(src + (e8 << 3));
#pragma unroll
    for (int e = 0; e < 8; ++e) { float x = b2f(a[e8][e]); ss += x * x; }
  }
  ss += __shfl_xor(ss, 1);
  ss += __shfl_xor(ss, 2);
  float inv = rsqrtf(ss * (1.f / 128.f) + 1e-6f);
  u16* dp = onb + ((size_t)((tt << 6) + t) << 11) + (h << 7) + (dg << 5);
#pragma unroll
  for (int e8 = 0; e8 < 4; ++e8) {
    u16x8 p;
#pragma unroll
    for (int e = 0; e < 8; ++e)
      p[e] = f2b(b2f(a[e8][e]) * inv * wl[(dg << 5) + (e8 << 3) + e]);
    *(u16x8*)(dp + (e8 << 3)) = p;
  }
}

extern "C" void kernel_launch(void* const* d_in, const int* in_sizes, int n_in,
                              void* d_out, int out_size, void* d_ws, size_t ws_size,
                              hipStream_t stream) {
  (void)in_sizes; (void)n_in; (void)out_size; (void)ws_size;
  const float* hs  = (const float*)d_in[0];
  const float* Wq  = (const float*)d_in[1];
  const float* Wk  = (const float*)d_in[2];
  const float* Wv  = (const float*)d_in[3];
  const float* Wb  = (const float*)d_in[4];
  const float* cwq = (const float*)d_in[5];
  const float* cwk = (const float*)d_in[6];
  const float* cwv = (const float*)d_in[7];
  const float* onw = (const float*)d_in[8];
  const float* Wo  = (const float*)d_in[9];
  float* out = (float*)d_out;
  char* ws = (char*)d_ws;
  const size_t MB = 1ull << 20;
  u16*  Xb   = (u16*)(ws);              //  8 MB  hs bf16 [2048][2048]
  u16*  WT   = (u16*)(ws + 8  * MB);    // 24 MB  [Wq|Wk|Wv]^T bf16 [6144][2048]
  u16*  WoT  = (u16*)(ws + 32 * MB);    //  8 MB  Wo^T bf16
  u16*  QKV  = (u16*)(ws + 40 * MB);    // 24 MB  qkv pre-activations (dead after k_convbeta)
  u16*  Wg   = (u16*)(ws + 40 * MB);    //  8 MB  overlays dead QKV
  u16*  KTg  = (u16*)(ws + 48 * MB);    //  8 MB
  u16*  UTg  = (u16*)(ws + 56 * MB);    //  8 MB
  u16*  qn_  = (u16*)(ws + 64 * MB);    //  8 MB  [16][2048][128]
  u16*  kn_  = (u16*)(ws + 72 * MB);    //  8 MB
  u16*  vn_  = (u16*)(ws + 80 * MB);    //  8 MB
  float* beta= (float*)(ws + 88 * MB);  //  128KB [2048][16]
  u16*  WbT  = (u16*)(ws + 88 * MB + 512 * 1024);  // 64KB [16][2048]
  u16*  Gm   = (u16*)(ws + 89 * MB);    //  4 MB  [32*16][64][64]
  u16*  o_   = (u16*)(ws + 93 * MB);    //  8 MB  bf16 [16][2048][128]
  u16*  onb  = (u16*)(ws + 109 * MB);   //  8 MB  [2048][2048]

  k_pre<<<8320, 256, 0, stream>>>(hs, Xb, Wb, WbT, Wq, Wk, Wv, Wo, WT, WoT);
  k_gemm8p<<<dim3(24, 8), 512, 0, stream>>>(Xb, WT, QKV, 6144, 2048);
  k_convbeta<<<1664, 256, 0, stream>>>(QKV, cwq, cwk, cwv, qn_, kn_, vn_, Xb, WbT, beta);
  k_prep<<<dim3(16, 32), 256, 0, stream>>>(qn_, kn_, vn_, beta, Gm, Wg, KTg, UTg);
  k_delta<<<128, 256, 0, stream>>>(qn_, Wg, Gm, KTg, UTg, o_);
  k_onorm<<<dim3(32, 16), 256, 0, stream>>>(o_, onw, onb);
  k_gemm_wo<<<dim3(32, 32), 256, 0, stream>>>(onb, WoT, out, 2048, 2048, 2048);
}

// Round 9
// 326.239 us; speedup vs baseline: 1.0676x; 1.0023x over previous
//
#include <hip/hip_runtime.h>

typedef unsigned short u16;
typedef __attribute__((ext_vector_type(4))) unsigned short u16x4;
typedef __attribute__((ext_vector_type(8))) unsigned short u16x8;
typedef __attribute__((ext_vector_type(8))) short short8;
typedef __attribute__((ext_vector_type(4))) float f32x4;

#define DEVI __device__ __forceinline__

DEVI u16 f2b(float f) {
  union { float f; unsigned u; } x; x.f = f;
  unsigned r = (x.u + 0x7fffu + ((x.u >> 16) & 1u)) >> 16;
  return (u16)r;
}
DEVI float b2f(u16 h) {
  union { unsigned u; float f; } x; x.u = ((unsigned)h) << 16;
  return x.f;
}
DEVI f32x4 mfma_bf16(short8 a, short8 b, f32x4 c) {
  return __builtin_amdgcn_mfma_f32_16x16x32_bf16(a, b, c, 0, 0, 0);
}
DEVI void gl2lds16(const u16* g, u16* l) {
  __builtin_amdgcn_global_load_lds((__attribute__((address_space(1))) void*)g,
                                   (__attribute__((address_space(3))) void*)l,
                                   16, 0, 0);
}
// barrier that drains only LDS (lgkmcnt), NOT vmcnt -> global prefetch stays in flight
DEVI void barrier_lds() {
  asm volatile("s_waitcnt lgkmcnt(0)\n\ts_barrier" ::: "memory");
}

// ---- fused input prep: fp32->bf16 cvt (hs) + WbT build + 4x 64x64-tile transpose ----
// blocks [0,4096): hs cvt; [4096,4224): WbT; [4224,8320): transposes of Wq/Wk/Wv/Wo.
__global__ __launch_bounds__(256)
void k_pre(const float* __restrict__ hs, u16* __restrict__ Xb,
           const float* __restrict__ Wb, u16* __restrict__ WbT,
           const float* __restrict__ Wq, const float* __restrict__ Wk,
           const float* __restrict__ Wv, const float* __restrict__ Wo,
           u16* __restrict__ WT, u16* __restrict__ WoT) {
  __shared__ u16 tile[64 * 66];
  int b = blockIdx.x;
  if (b < 4096) {
    int i = b * 256 + threadIdx.x;
    float4 v = ((const float4*)hs)[i];
    u16x4 r; r.x = f2b(v.x); r.y = f2b(v.y); r.z = f2b(v.z); r.w = f2b(v.w);
    ((u16x4*)Xb)[i] = r;
    return;
  }
  if (b < 4224) {
    int j = (b - 4096) * 256 + threadIdx.x;   // 0..32767
    int n = j >> 11, k = j & 2047;
    WbT[j] = f2b(Wb[k * 16 + n]);
    return;
  }
  const int RC = 2048;
  int tb = b - 4224;                  // 0..4095
  int z = tb >> 10, t = tb & 1023;
  const float* src = (z == 0) ? Wq : (z == 1) ? Wk : (z == 2) ? Wv : Wo;
  u16* dst = (z == 0) ? WT : (z == 1) ? (WT + 2048 * 2048)
           : (z == 2) ? (WT + 2 * 2048 * 2048) : WoT;
  int bx = (t & 31) << 6, by = (t >> 5) << 6;
  int x = threadIdx.x & 63, g = threadIdx.x >> 6;
#pragma unroll
  for (int i = 0; i < 16; ++i) {
    int r = (i << 2) + g;
    tile[x * 66 + r] = f2b(src[(size_t)(by + r) * RC + bx + x]);  // transposed into LDS
  }
  __syncthreads();
#pragma unroll
  for (int i = 0; i < 16; ++i) {
    int r = (i << 2) + g;
    dst[(size_t)(bx + r) * RC + by + x] = tile[r * 66 + x];       // 128B coalesced rows
  }
}

// ============ 8-phase 256x256 bf16 MFMA GEMM, ds_reads pipelined one phase ahead ============
// (round-2 schedule — measured best at 59.9us; cross-session variance +-10% observed on
//  identical code (60.9 R5 vs 67.5 R8). 1 barrier/phase, reads issued one phase before use,
//  compiler emits counted lgkmcnt. sched_barrier pinning tested: neutral; m201-style
//  2-barrier + lgkmcnt(0): regression. Do not re-add without new evidence.)
// C[M][N] = A[M][K] @ BT[N][K]^T. BM=BN=256, BK=64, 512 thr = 8 waves (2x4).
// LDS 128 KiB = {A0,A1,B0,B1} x {slot0,slot1} x (128 rows x 64 k) bf16.
// vmcnt(4) at phi2-end proves all four halves of tile u+1 landed before phi3 issues
// next-tile reads. Stage order: phi0->A1(u+1), phi1->A0(u+2), phi2->B0(u+2), phi3->B1(u+2).
// LDS XOR-swizzled reads; inverse swizzle on the per-lane GLOBAL source (rule 21).

struct StageCtx { size_t go[2]; int lo[2]; };

DEVI void stage_half(const u16* g, const StageCtx& sc, u16* l) {
  gl2lds16(g + sc.go[0], l + sc.lo[0]);
  gl2lds16(g + sc.go[1], l + sc.lo[1]);
}

DEVI void rdA(const u16* h, const int (&aoff)[4][2], short8 (&a)[4][2]) {
#pragma unroll
  for (int m = 0; m < 4; ++m) {
    a[m][0] = *(const short8*)(h + aoff[m][0]);
    a[m][1] = *(const short8*)(h + aoff[m][1]);
  }
}
DEVI void rdB(const u16* h, const int (&boff)[2][2], short8 (&b)[2][2]) {
#pragma unroll
  for (int n = 0; n < 2; ++n) {
    b[n][0] = *(const short8*)(h + boff[n][0]);
    b[n][1] = *(const short8*)(h + boff[n][1]);
  }
}

template <int QA, int QB>
DEVI void mmquad(const short8 (&a)[4][2], const short8 (&b)[2][2], f32x4 (&acc)[8][4]) {
  __builtin_amdgcn_s_setprio(1);
#pragma unroll
  for (int m = 0; m < 4; ++m)
#pragma unroll
    for (int n = 0; n < 2; ++n) {
      acc[(QA << 2) + m][(QB << 1) + n] =
          mfma_bf16(a[m][0], b[n][0], acc[(QA << 2) + m][(QB << 1) + n]);
      acc[(QA << 2) + m][(QB << 1) + n] =
          mfma_bf16(a[m][1], b[n][1], acc[(QA << 2) + m][(QB << 1) + n]);
    }
  __builtin_amdgcn_s_setprio(0);
}

template <int MODE>  // 0 = steady, 1 = u == NT-2, 2 = u == NT-1
DEVI void ktile(u16* lds, int u,
                const u16* gA0, const u16* gA1, const u16* gB0, const u16* gB1,
                const StageCtx& sc,
                const int (&aoff)[4][2], const int (&boff)[2][2],
                short8 (&a0)[4][2], short8 (&a1)[4][2],
                short8 (&b0)[2][2], short8 (&b1)[2][2],
                f32x4 (&acc)[8][4]) {
  const int cs = (u & 1) << 13, ns = ((u + 1) & 1) << 13;
  const u16* A1c = lds + 16384 + cs;
  const u16* B1c = lds + 49152 + cs;
  const size_t uo1 = (size_t)(u + 1) << 6, uo2 = (size_t)(u + 2) << 6;
  // ---- phase 0: MFMA quad(0,0) = a0*b0; issue RB1(u); stage A1(u+1)
  __builtin_amdgcn_s_barrier();
  rdB(B1c, boff, b1);
  if constexpr (MODE <= 1) stage_half(gA1 + uo1, sc, lds + 16384 + ns);
  mmquad<0, 0>(a0, b0, acc);
  // ---- phase 1: MFMA quad(0,1) = a0*b1; issue RA1(u); stage A0(u+2)
  __builtin_amdgcn_s_barrier();
  rdA(A1c, aoff, a1);
  if constexpr (MODE == 0) stage_half(gA0 + uo2, sc, lds + cs);
  mmquad<0, 1>(a0, b1, acc);
  // ---- phase 2: MFMA quad(1,0) = a1*b0; stage B0(u+2); counted vmcnt
  __builtin_amdgcn_s_barrier();
  if constexpr (MODE == 0) stage_half(gB0 + uo2, sc, lds + 32768 + cs);
  mmquad<1, 0>(a1, b0, acc);
  if constexpr (MODE == 0) asm volatile("s_waitcnt vmcnt(4)" ::: "memory");
  if constexpr (MODE == 1) asm volatile("s_waitcnt vmcnt(0)" ::: "memory");
  // ---- phase 3: MFMA quad(1,1) = a1*b1; issue next-tile RA0/RB0; stage B1(u+2)
  __builtin_amdgcn_s_barrier();
  if constexpr (MODE <= 1) {
    rdA(lds + ns, aoff, a0);
    rdB(lds + 32768 + ns, boff, b0);
  }
  if constexpr (MODE == 0) stage_half(gB1 + uo2, sc, lds + 49152 + cs);
  mmquad<1, 1>(a1, b1, acc);
}

__global__ __launch_bounds__(512, 2)
void k_gemm8p(const u16* __restrict__ A, const u16* __restrict__ BT,
              u16* __restrict__ Cb, int N, int K) {
  __shared__ __align__(16) u16 lds[65536];   // 128 KiB
  const int tid = threadIdx.x, wave = tid >> 6, lane = tid & 63;
  const int wm = wave >> 2, wn = wave & 3;
  const int fr = lane & 15, fq = (lane >> 4) << 4;   // fq in BYTES
  const long bm = (long)blockIdx.y << 8, bn = (long)blockIdx.x << 8;
  const int NT = K >> 6;
  // precomputed swizzled LDS read offsets (u16 units), loop-invariant
  int aoff[4][2], boff[2][2];
#pragma unroll
  for (int m = 0; m < 4; ++m)
#pragma unroll
    for (int ks = 0; ks < 2; ++ks) {
      int row = (wm << 6) + (m << 4) + fr;
      int kb = (ks << 6) + fq;
      aoff[m][ks] = (row << 6) + ((kb ^ ((fr & 7) << 4)) >> 1);
    }
#pragma unroll
  for (int n = 0; n < 2; ++n)
#pragma unroll
    for (int ks = 0; ks < 2; ++ks) {
      int row = (wn << 5) + (n << 4) + fr;
      int kb = (ks << 6) + fq;
      boff[n][ks] = (row << 6) + ((kb ^ ((fr & 7) << 4)) >> 1);
    }
  // stage context: linear LDS dest, inverse-swizzled global source
  StageCtx sc;
#pragma unroll
  for (int s = 0; s < 2; ++s) {
    int c = (s << 9) + tid, row = c >> 3;
    int kbs = (((c & 7) << 4) ^ ((row & 7) << 4));
    sc.go[s] = (size_t)row * K + (kbs >> 1);
    sc.lo[s] = ((s << 9) + (tid & ~63)) << 3;
  }
  const u16* gA0 = A + (size_t)bm * K;
  const u16* gA1 = gA0 + (size_t)128 * K;
  const u16* gB0 = BT + (size_t)bn * K;
  const u16* gB1 = gB0 + (size_t)128 * K;
  f32x4 acc[8][4];
#pragma unroll
  for (int i = 0; i < 8; ++i)
#pragma unroll
    for (int j = 0; j < 4; ++j) acc[i][j] = (f32x4){0.f, 0.f, 0.f, 0.f};
  short8 a0[4][2], a1[4][2], b0[2][2], b1[2][2];
  // prologue: tile 0 all 4 halves, then A0/B0/B1 of tile 1 (A1(1) staged at phi0 of u=0)
  stage_half(gA0, sc, lds + 0);
  stage_half(gA1, sc, lds + 16384);
  stage_half(gB0, sc, lds + 32768);
  stage_half(gB1, sc, lds + 49152);
  stage_half(gA0 + 64, sc, lds + 8192);
  stage_half(gB0 + 64, sc, lds + 32768 + 8192);
  stage_half(gB1 + 64, sc, lds + 49152 + 8192);
  asm volatile("s_waitcnt vmcnt(6)" ::: "memory");   // tile-0's 8 loads landed (own wave)
  __builtin_amdgcn_s_barrier();                      // cross-wave landing
  rdA(lds + 0, aoff, a0);                            // RA0(0)
  rdB(lds + 32768, boff, b0);                        // RB0(0)
  for (int u = 0; u + 2 < NT; ++u)
    ktile<0>(lds, u, gA0, gA1, gB0, gB1, sc, aoff, boff, a0, a1, b0, b1, acc);
  ktile<1>(lds, NT - 2, gA0, gA1, gB0, gB1, sc, aoff, boff, a0, a1, b0, b1, acc);
  ktile<2>(lds, NT - 1, gA0, gA1, gB0, gB1, sc, aoff, boff, a0, a1, b0, b1, acc);
  // epilogue: C/D map col=lane&15 (B side), row=(lane>>4)*4+r (A side)
  const int er = (lane >> 4) << 2, ec = lane & 15;
#pragma unroll
  for (int ai = 0; ai < 8; ++ai) {
    long row0 = bm + ((long)(ai >> 2) << 7) + (wm << 6) + ((ai & 3) << 4) + er;
#pragma unroll
    for (int bj = 0; bj < 4; ++bj) {
      long col = bn + ((long)(bj >> 1) << 7) + (wn << 5) + ((bj & 1) << 4) + ec;
#pragma unroll
      for (int r = 0; r < 4; ++r)
        Cb[(size_t)(row0 + r) * N + col] = f2b(acc[ai][bj][r]);
    }
  }
}

// ---------------- bf16 MFMA GEMM 64x64 tile (max block count for small GEMMs) ----------------
// (split-K=4 + add4 alternative tested R3/R4: wash vs this — add4's 80MB round-trip eats
//  the GEMM gain. Keep.)
__global__ __launch_bounds__(256, 4)
void k_gemm_wo(const u16* __restrict__ A, const u16* __restrict__ BT,
               float* __restrict__ Cf, int M, int N, int K) {
  __shared__ __align__(16) u16 As[2048];
  __shared__ __align__(16) u16 Bs[2048];
  const int tid = threadIdx.x, wave = tid >> 6, lane = tid & 63;
  const long bm = (long)blockIdx.y << 6, bn = (long)blockIdx.x << 6;
  const int r0 = (wave << 4) + (lane >> 2);
  const int kof = (((lane & 3) ^ ((lane >> 3) & 3)) << 3);
  const u16* gA = A + (bm + r0) * (long)K + kof;
  const u16* gB = BT + (bn + r0) * (long)K + kof;
  u16* lA = As + (wave << 9);
  u16* lB = Bs + (wave << 9);
  const int wr = (wave >> 1) << 5, wc = (wave & 1) << 5;
  const int fr = lane & 15, fq = (lane >> 4) << 3;
  const int fqs = fq ^ (((fr >> 1) & 3) << 3);
  f32x4 acc[2][2];
#pragma unroll
  for (int i = 0; i < 2; ++i)
#pragma unroll
    for (int j = 0; j < 2; ++j) acc[i][j] = (f32x4){0.f, 0.f, 0.f, 0.f};
  for (int k0 = 0; k0 < K; k0 += 32) {
    gl2lds16(gA + k0, lA);
    gl2lds16(gB + k0, lB);
    __syncthreads();
    short8 af[2], bfr[2];
#pragma unroll
    for (int t = 0; t < 2; ++t) {
      af[t]  = *(const short8*)&As[(wr + (t << 4) + fr) * 32 + fqs];
      bfr[t] = *(const short8*)&Bs[(wc + (t << 4) + fr) * 32 + fqs];
    }
#pragma unroll
    for (int i = 0; i < 2; ++i)
#pragma unroll
      for (int j = 0; j < 2; ++j)
        acc[i][j] = mfma_bf16(af[i], bfr[j], acc[i][j]);
    __syncthreads();
  }
  const int er = (lane >> 4) << 2, ec = lane & 15;
#pragma unroll
  for (int i = 0; i < 2; ++i)
#pragma unroll
    for (int j = 0; j < 2; ++j)
#pragma unroll
      for (int r = 0; r < 4; ++r) {
        long row = bm + wr + (i << 4) + er + r;
        long col = bn + wc + (j << 4) + ec;
        Cf[row * N + col] = acc[i][j][r];
      }
}

// ---------------- causal conv(K=4)+SiLU+l2norm (1536 blocks) + beta (128 blocks) ----------------
// beta scratch: 4 waves x 256 floats = 4 KiB. MUST be >= 4096 B (round-6 bug: passed the
// 2 KiB wf array -> overflow corrupted beta). Beta blocks never touch xs (18 KiB), so xs
// serves as the scratch.
DEVI void beta_body(const u16* __restrict__ Xb, const u16* __restrict__ WbT,
                    float* __restrict__ beta, int bb, float* part) {
  int tid = threadIdx.x, w = tid >> 6, lane = tid & 63;
  int t0 = bb << 4;
  int fr = lane & 15, fq = (lane >> 4) << 3;
  const u16* ap = Xb + (size_t)(t0 + fr) * 2048 + (w << 9) + fq;
  const u16* bp = WbT + (size_t)fr * 2048 + (w << 9) + fq;
  f32x4 acc = {0.f, 0.f, 0.f, 0.f};
#pragma unroll
  for (int ks = 0; ks < 16; ++ks)
    acc = mfma_bf16(*(const short8*)(ap + (ks << 5)), *(const short8*)(bp + (ks << 5)), acc);
  int er = (lane >> 4) << 2;
#pragma unroll
  for (int r = 0; r < 4; ++r) part[w * 256 + (er + r) * 16 + fr] = acc[r];
  __syncthreads();
  float s = part[tid] + part[256 + tid] + part[512 + tid] + part[768 + tid];
  beta[(t0 << 4) + tid] = 1.f / (1.f + __expf(-s));
}

__global__ __launch_bounds__(256, 4)
void k_convbeta(const u16* __restrict__ qkv,
                const float* __restrict__ cwq, const float* __restrict__ cwk,
                const float* __restrict__ cwv,
                u16* __restrict__ qn, u16* __restrict__ kn, u16* __restrict__ vn,
                const u16* __restrict__ Xb, const u16* __restrict__ WbT,
                float* __restrict__ beta) {
  __shared__ __align__(16) u16 xs[67 * 136];   // 18224 B; beta blocks reuse as 4KB scratch
  __shared__ float wf[128 * 4];
  int b = blockIdx.x;
  if (b >= 1536) { beta_body(Xb, WbT, beta, b - 1536, (float*)xs); return; }
  int tt = b & 31, s = b >> 5;
  int kind = s >> 4, h = s & 15;
  int t0 = tt << 6;
  int col = (kind << 11) + (h << 7);
  int tid = threadIdx.x;
  const float* cw = (kind == 0) ? cwq : ((kind == 1) ? cwk : cwv);
  if (tid < 128) *(float4*)&wf[tid << 2] = *(const float4*)(cw + (size_t)((h << 7) + tid) * 4);
  // stage rows t0-3 .. t0+63 (67 rows x 128 d), coalesced 16B chunks
  for (int i = tid; i < 1072; i += 256) {
    int prow = i >> 4, c8 = (i & 15) << 3;
    int g = t0 - 3 + prow;
    u16x8 v = {0, 0, 0, 0, 0, 0, 0, 0};
    if (g >= 0) v = *(const u16x8*)(qkv + (size_t)g * 6144 + col + c8);
    *(u16x8*)&xs[prow * 136 + c8] = v;
  }
  __syncthreads();
  int t = tid >> 2, dg = tid & 3;
  float y[32];
  float ss = 0.f;
#pragma unroll
  for (int e8 = 0; e8 < 4; ++e8) {
    int d0 = (dg << 5) + (e8 << 3);
    u16x8 a0 = *(const u16x8*)&xs[(t + 0) * 136 + d0];
    u16x8 a1 = *(const u16x8*)&xs[(t + 1) * 136 + d0];
    u16x8 a2 = *(const u16x8*)&xs[(t + 2) * 136 + d0];
    u16x8 a3 = *(const u16x8*)&xs[(t + 3) * 136 + d0];
#pragma unroll
    for (int e = 0; e < 8; ++e) {
      float4 w = *(const float4*)&wf[(d0 + e) << 2];
      float v = b2f(a0[e]) * w.x + b2f(a1[e]) * w.y + b2f(a2[e]) * w.z + b2f(a3[e]) * w.w;
      v = v / (1.f + __expf(-v));   // SiLU
      y[(e8 << 3) + e] = v;
      ss += v * v;
    }
  }
  float sc = 1.f;
  if (kind < 2) {
    ss += __shfl_xor(ss, 1);
    ss += __shfl_xor(ss, 2);
    sc = rsqrtf(ss + 1e-6f);
    if (kind == 0) sc *= 0.08838834764831843f;  // 128^-0.5
  }
  u16* dst = (kind == 0) ? qn : ((kind == 1) ? kn : vn);
  u16* dp = dst + ((size_t)h << 18) + ((size_t)(t0 + t) << 7) + (dg << 5);
#pragma unroll
  for (int e8 = 0; e8 < 4; ++e8) {
    u16x8 p;
#pragma unroll
    for (int e = 0; e < 8; ++e) p[e] = f2b(y[(e8 << 3) + e] * sc);
    *(u16x8*)(dp + (e8 << 3)) = p;
  }
}

// ---------------- per-(chunk,head) parallel prep (v3) ----------------
// Forward substitution X = (I + tril(A))^{-1} b with X in VGPRs (FSub template recursion,
// R8). R8 post-mortem: __launch_bounds__(256,2) caps the allocator at ~128 VGPR; X[64] +
// temps need ~140+ -> partial spill remained (79 -> only ~64us). LDS (70912B) limits
// occupancy to 2 blocks/CU regardless of the bound, so (256,2) bought nothing but the cap.
// Now (256,1): VGPR budget 256, X fully register-resident; worst case 1 block/CU (bounded).
template <int R>
struct FSub {
  static DEVI void run(float (&X)[64], const float* __restrict__ AL) {
    const float* Ar = AL + R * 64;
    float s0 = 0.f, s1 = 0.f;
#pragma unroll
    for (int l = 0; l + 4 <= R; l += 4) {
      float4 a = *(const float4*)(Ar + l);
      s0 += a.x * X[l];
      s1 += a.y * X[l + 1];
      s0 += a.z * X[l + 2];
      s1 += a.w * X[l + 3];
    }
#pragma unroll
    for (int l = R & ~3; l < R; ++l) s0 += Ar[l] * X[l];
    X[R] -= s0 + s1;
    FSub<R + 1>::run(X, AL);
  }
};
template <>
struct FSub<64> { static DEVI void run(float (&)[64], const float*) {} };

__global__ __launch_bounds__(256, 1)
void k_prep(const u16* __restrict__ qn, const u16* __restrict__ kn, const u16* __restrict__ vn,
            const float* __restrict__ beta,
            u16* __restrict__ Gg, u16* __restrict__ Wg,
            u16* __restrict__ KTg, u16* __restrict__ UTg) {
  __shared__ __align__(16) char sm[70912];
  u16*  Kc  = (u16*)sm;                 // 64*136*2 = 17408
  u16*  Qc  = (u16*)(sm + 17408);       // 17408 ; overlay: WR
  u16*  Vc  = (u16*)(sm + 34816);       // 17408
  u16*  KTl = (u16*)(sm + 52224);       // 128*72*2 = 18432 ; overlay: AL (64*64*4)
  float* AL = (float*)(sm + 52224);
  float* Bl = (float*)(sm + 70656);     // 256
  u16*  WR  = Qc;
  int h = blockIdx.x, c = blockIdx.y;
  int tid = threadIdx.x, wave = tid >> 6, lane = tid & 63;
  size_t ch = (size_t)(c * 16 + h);
  const u16* kb = kn + ((size_t)h << 18) + ((size_t)c << 13);
  const u16* qb = qn + ((size_t)h << 18) + ((size_t)c << 13);
  const u16* vb = vn + ((size_t)h << 18) + ((size_t)c << 13);
#pragma unroll
  for (int s = 0; s < 4; ++s) {
    int e = (tid + (s << 8)) << 3;
    int t = e >> 7, d = e & 127;
    *(u16x8*)&Kc[t * 136 + d] = *(const u16x8*)(kb + e);
    *(u16x8*)&Qc[t * 136 + d] = *(const u16x8*)(qb + e);
    *(u16x8*)&Vc[t * 136 + d] = *(const u16x8*)(vb + e);
  }
  if (tid < 64) Bl[tid] = beta[((c << 6) + tid) * 16 + h];
  __syncthreads();
  int fr = lane & 15, fq = (lane >> 4) << 3, q4 = (lane >> 4) << 2;
  int arow = (wave << 4) + fr;
  f32x4 kk[4], qk[4];
#pragma unroll
  for (int ct = 0; ct < 4; ++ct) { kk[ct] = (f32x4){0.f,0.f,0.f,0.f}; qk[ct] = (f32x4){0.f,0.f,0.f,0.f}; }
#pragma unroll
  for (int ks = 0; ks < 4; ++ks) {
    short8 aK = *(const short8*)&Kc[arow * 136 + (ks << 5) + fq];
    short8 aQ = *(const short8*)&Qc[arow * 136 + (ks << 5) + fq];
#pragma unroll
    for (int ct = 0; ct < 4; ++ct) {
      short8 bK = *(const short8*)&Kc[((ct << 4) + fr) * 136 + (ks << 5) + fq];
      kk[ct] = mfma_bf16(aK, bK, kk[ct]);
      qk[ct] = mfma_bf16(aQ, bK, qk[ct]);
    }
  }
#pragma unroll
  for (int ct = 0; ct < 4; ++ct)
#pragma unroll
    for (int r = 0; r < 4; ++r) {
      int i = (wave << 4) + q4 + r, j = (ct << 4) + fr;
      Gg[(ch << 12) + i * 64 + j] = f2b((j <= i) ? qk[ct][r] : 0.f);
    }
  // K^T into KTl
  {
    int d = tid & 127, tg = tid >> 7;
#pragma unroll
    for (int it = 0; it < 4; ++it) {
      int t0 = (tg + (it << 1)) << 3;
      u16x8 pk;
#pragma unroll
      for (int j = 0; j < 8; ++j) pk[j] = Kc[(t0 + j) * 136 + d];
      *(u16x8*)&KTl[d * 72 + t0] = pk;
    }
  }
  __syncthreads();
#pragma unroll
  for (int it = 0; it < 4; ++it) {
    int idx = tid + (it << 8);
    int row = idx >> 3, j8 = (idx & 7) << 3;
    *(u16x8*)(KTg + (ch << 13) + (row << 6) + j8) = *(const u16x8*)&KTl[row * 72 + j8];
  }
  __syncthreads();
  {
    float bi[4];
#pragma unroll
    for (int r = 0; r < 4; ++r) bi[r] = Bl[(wave << 4) + q4 + r];
#pragma unroll
    for (int ct = 0; ct < 4; ++ct)
#pragma unroll
      for (int r = 0; r < 4; ++r) {
        int i = (wave << 4) + q4 + r, j = (ct << 4) + fr;
        AL[i * 64 + j] = (j < i) ? bi[r] * kk[ct][r] : 0.f;
      }
  }
  __syncthreads();
  float X[64];
  {
    const u16* colp = (tid < 128) ? (Kc + tid) : (Vc + (tid - 128));
#pragma unroll
    for (int t = 0; t < 64; ++t) X[t] = Bl[t] * b2f(colp[t * 136]);
    FSub<1>::run(X, AL);
  }
  __syncthreads();   // Qc dead -> WR overlay
  if (tid < 128) {
#pragma unroll
    for (int t = 0; t < 64; ++t) WR[t * 136 + tid] = f2b(X[t]);
  } else {
    int v = tid - 128;
    u16* dstr = UTg + (ch << 13) + (v << 6);
#pragma unroll
    for (int j = 0; j < 8; ++j) {
      u16x8 p;
#pragma unroll
      for (int e = 0; e < 8; ++e) p[e] = f2b(X[(j << 3) + e]);
      *(u16x8*)(dstr + (j << 3)) = p;
    }
  }
  __syncthreads();
#pragma unroll
  for (int it = 0; it < 4; ++it) {
    int idx = tid + (it << 8);
    int row = idx >> 4, j8 = (idx & 15) << 3;
    *(u16x8*)(Wg + (ch << 13) + (row << 7) + j8) = *(const u16x8*)&WR[row * 136 + j8];
  }
}

// ---------------- sequential chunked delta-rule scan (lean) ----------------
struct Frags { short8 q[4], w[4], g[2], k[4]; u16x4 u; };

DEVI void load_frags(Frags& f, const u16* qh, const u16* Wg, const u16* Gg,
                     const u16* KTg, const u16* UTg, int c, int h,
                     int trow, int fr, int fq, int q4, int w, int vbase) {
  const u16* qb = qh + ((size_t)((c << 6) + trow + fr) << 7) + fq;
#pragma unroll
  for (int ks = 0; ks < 4; ++ks) f.q[ks] = *(const short8*)(qb + (ks << 5));
  size_t ch = (size_t)(c * 16 + h);
  const u16* wb = Wg + (ch << 13) + ((size_t)(trow + fr) << 7) + fq;
#pragma unroll
  for (int ks = 0; ks < 4; ++ks) f.w[ks] = *(const short8*)(wb + (ks << 5));
  const u16* gb = Gg + (ch << 12) + ((size_t)(trow + fr) << 6) + fq;
#pragma unroll
  for (int ks = 0; ks < 2; ++ks) f.g[ks] = *(const short8*)(gb + (ks << 5));
  const u16* kbp = KTg + (ch << 13) + ((size_t)(w << 5) << 6) + fq;
#pragma unroll
  for (int dt = 0; dt < 2; ++dt)
#pragma unroll
    for (int ks = 0; ks < 2; ++ks)
      f.k[(dt << 1) | ks] = *(const short8*)(kbp + ((size_t)((dt << 4) + fr) << 6) + (ks << 5));
  f.u = *(const u16x4*)(UTg + (ch << 13) + ((size_t)(vbase + fr) << 6) + trow + q4);
}

DEVI void chunk_body(int c, Frags& f, u16* ST, u16* DT, u16* oh,
                     int trow, int fr, int fq, int q4, int w, int vbase,
                     f32x4& S0, f32x4& S1) {
#pragma unroll
  for (int r = 0; r < 4; ++r) {
    ST[(q4 + r) * 136 + (w << 5) + fr] = f2b(S0[r]);
    ST[(q4 + r) * 136 + (w << 5) + 16 + fr] = f2b(S1[r]);
  }
  barrier_lds();
  short8 sf[4];
#pragma unroll
  for (int ks = 0; ks < 4; ++ks) sf[ks] = *(const short8*)&ST[fr * 136 + (ks << 5) + fq];
  f32x4 racc = {0.f,0.f,0.f,0.f}, oacc = {0.f,0.f,0.f,0.f};
#pragma unroll
  for (int ks = 0; ks < 4; ++ks) {
    racc = mfma_bf16(f.w[ks], sf[ks], racc);
    oacc = mfma_bf16(f.q[ks], sf[ks], oacc);
  }
#pragma unroll
  for (int r = 0; r < 4; ++r)
    DT[fr * 72 + trow + q4 + r] = f2b(b2f(f.u[r]) - racc[r]);
  barrier_lds();
  short8 df[2];
#pragma unroll
  for (int ks = 0; ks < 2; ++ks) df[ks] = *(const short8*)&DT[fr * 72 + (ks << 5) + fq];
#pragma unroll
  for (int ks = 0; ks < 2; ++ks) {
    oacc = mfma_bf16(f.g[ks], df[ks], oacc);
    S0 = mfma_bf16(df[ks], f.k[ks], S0);
    S1 = mfma_bf16(df[ks], f.k[2 | ks], S1);
  }
#pragma unroll
  for (int r = 0; r < 4; ++r)
    oh[(size_t)((c << 6) + trow + q4 + r) * 128 + vbase + fr] = f2b(oacc[r]);
}

__global__ __launch_bounds__(256, 1)
void k_delta(const u16* __restrict__ qn, const u16* __restrict__ Wg,
             const u16* __restrict__ Gg, const u16* __restrict__ KTg,
             const u16* __restrict__ UTg, u16* __restrict__ o) {
  __shared__ __align__(16) u16 ST[16 * 136];
  __shared__ __align__(16) u16 DT[16 * 72];
  int bx = blockIdx.x;
  int h = bx & 15, vbase = (bx >> 4) << 4;
  int tid = threadIdx.x, w = tid >> 6, lane = tid & 63;
  int fr = lane & 15, fq = (lane >> 4) << 3, q4 = (lane >> 4) << 2;
  int trow = w << 4;
  const u16* qh = qn + ((size_t)h << 18);
  u16* oh = o + ((size_t)h << 18);
  f32x4 S0 = {0.f,0.f,0.f,0.f}, S1 = {0.f,0.f,0.f,0.f};
  Frags fa, fb;
  load_frags(fa, qh, Wg, Gg, KTg, UTg, 0, h, trow, fr, fq, q4, w, vbase);
  for (int c = 0; c < 32; c += 2) {
    int c1 = c + 1, c2 = (c + 2 < 32) ? c + 2 : 31;
    load_frags(fb, qh, Wg, Gg, KTg, UTg, c1, h, trow, fr, fq, q4, w, vbase);
    chunk_body(c, fa, ST, DT, oh, trow, fr, fq, q4, w, vbase, S0, S1);
    load_frags(fa, qh, Wg, Gg, KTg, UTg, c2, h, trow, fr, fq, q4, w, vbase);
    chunk_body(c1, fb, ST, DT, oh, trow, fr, fq, q4, w, vbase, S0, S1);
  }
}

// ---------------- per-head RMSNorm on o (bf16), tile version ----------------
// grid (32, 16): 64-token tile x head. thread = (token, 32-d group).
__global__ __launch_bounds__(256, 4)
void k_onorm(const u16* __restrict__ o, const float* __restrict__ onw,
             u16* __restrict__ onb) {
  __shared__ float wl[128];
  int tt = blockIdx.x, h = blockIdx.y, tid = threadIdx.x;
  if (tid < 128) wl[tid] = onw[tid];
  __syncthreads();
  int t = tid >> 2, dg = tid & 3;
  const u16* src = o + ((size_t)h << 18) + ((size_t)((tt << 6) + t) << 7) + (dg << 5);
  u16x8 a[4];
  float ss = 0.f;
#pragma unroll
  for (int e8 = 0; e8 < 4; ++e8) {
    a[e8] = *(const u16x8*)(src + (e8 << 3));
#pragma unroll
    for (int e = 0; e < 8; ++e) { float x = b2f(a[e8][e]); ss += x * x; }
  }
  ss += __shfl_xor(ss, 1);
  ss += __shfl_xor(ss, 2);
  float inv = rsqrtf(ss * (1.f / 128.f) + 1e-6f);
  u16* dp = onb + ((size_t)((tt << 6) + t) << 11) + (h << 7) + (dg << 5);
#pragma unroll
  for (int e8 = 0; e8 < 4; ++e8) {
    u16x8 p;
#pragma unroll
    for (int e = 0; e < 8; ++e)
      p[e] = f2b(b2f(a[e8][e]) * inv * wl[(dg << 5) + (e8 << 3) + e]);
    *(u16x8*)(dp + (e8 << 3)) = p;
  }
}

extern "C" void kernel_launch(void* const* d_in, const int* in_sizes, int n_in,
                              void* d_out, int out_size, void* d_ws, size_t ws_size,
                              hipStream_t stream) {
  (void)in_sizes; (void)n_in; (void)out_size; (void)ws_size;
  const float* hs  = (const float*)d_in[0];
  const float* Wq  = (const float*)d_in[1];
  const float* Wk  = (const float*)d_in[2];
  const float* Wv  = (const float*)d_in[3];
  const float* Wb  = (const float*)d_in[4];
  const float* cwq = (const float*)d_in[5];
  const float* cwk = (const float*)d_in[6];
  const float* cwv = (const float*)d_in[7];
  const float* onw = (const float*)d_in[8];
  const float* Wo  = (const float*)d_in[9];
  float* out = (float*)d_out;
  char* ws = (char*)d_ws;
  const size_t MB = 1ull << 20;
  u16*  Xb   = (u16*)(ws);              //  8 MB  hs bf16 [2048][2048]
  u16*  WT   = (u16*)(ws + 8  * MB);    // 24 MB  [Wq|Wk|Wv]^T bf16 [6144][2048]
  u16*  WoT  = (u16*)(ws + 32 * MB);    //  8 MB  Wo^T bf16
  u16*  QKV  = (u16*)(ws + 40 * MB);    // 24 MB  qkv pre-activations (dead after k_convbeta)
  u16*  Wg   = (u16*)(ws + 40 * MB);    //  8 MB  overlays dead QKV
  u16*  KTg  = (u16*)(ws + 48 * MB);    //  8 MB
  u16*  UTg  = (u16*)(ws + 56 * MB);    //  8 MB
  u16*  qn_  = (u16*)(ws + 64 * MB);    //  8 MB  [16][2048][128]
  u16*  kn_  = (u16*)(ws + 72 * MB);    //  8 MB
  u16*  vn_  = (u16*)(ws + 80 * MB);    //  8 MB
  float* beta= (float*)(ws + 88 * MB);  //  128KB [2048][16]
  u16*  WbT  = (u16*)(ws + 88 * MB + 512 * 1024);  // 64KB [16][2048]
  u16*  Gm   = (u16*)(ws + 89 * MB);    //  4 MB  [32*16][64][64]
  u16*  o_   = (u16*)(ws + 93 * MB);    //  8 MB  bf16 [16][2048][128]
  u16*  onb  = (u16*)(ws + 109 * MB);   //  8 MB  [2048][2048]

  k_pre<<<8320, 256, 0, stream>>>(hs, Xb, Wb, WbT, Wq, Wk, Wv, Wo, WT, WoT);
  k_gemm8p<<<dim3(24, 8), 512, 0, stream>>>(Xb, WT, QKV, 6144, 2048);
  k_convbeta<<<1664, 256, 0, stream>>>(QKV, cwq, cwk, cwv, qn_, kn_, vn_, Xb, WbT, beta);
  k_prep<<<dim3(16, 32), 256, 0, stream>>>(qn_, kn_, vn_, beta, Gm, Wg, KTg, UTg);
  k_delta<<<128, 256, 0, stream>>>(qn_, Wg, Gm, KTg, UTg, o_);
  k_onorm<<<dim3(32, 16), 256, 0, stream>>>(o_, onw, onb);
  k_gemm_wo<<<dim3(32, 32), 256, 0, stream>>>(onb, WoT, out, 2048, 2048, 2048);
}